// Round 1
// baseline (576.567 us; speedup 1.0000x reference)
//
#include <hip/hip_runtime.h>
#include <math.h>

// Renderer: occupancy-field ray marching + secant + shading, 1 block per ray.
// N=4096 rays, H=128 hidden, 128 ray steps, 8 secant iters, 96 shading samples.

namespace {

constexpr int H_    = 128;
constexpr int RS    = 128;   // RAY_STEPS
constexpr int NSEC  = 8;
constexpr int SOUT_ = 32;    // STEPS_OUT
constexpr int SIN_  = 64;    // STEPS_IN
constexpr int FULL_ = 96;
constexpr float TAU_   = 0.5f;
constexpr float EPSA   = 1e-6f;
// DELTA = max(2*exp(-1.5e-5*100000), 0.1) computed in double on host side
constexpr float DELTA_ = 0.44626032029685964f;

__device__ __forceinline__ float softplus_f(float x) {
    // stable: max(x,0) + log1p(exp(-|x|))  (matches jax.nn.softplus numerics)
    return fmaxf(x, 0.0f) + log1pf(expf(-fabsf(x)));
}
__device__ __forceinline__ float sigmoid_f(float x) {
    return 1.0f / (1.0f + expf(-x));
}
__device__ __forceinline__ float secant_step(float f_l, float f_h, float d_l, float d_h) {
    float den = f_h - f_l;
    if (fabsf(den) > 1e-12f) return -f_l * (d_h - d_l) / den + d_l;
    return 0.5f * (d_l + d_h);
}

__device__ void inv4(const float* m, float* o) {
    float inv[16];
    inv[0]  =  m[5]*m[10]*m[15] - m[5]*m[11]*m[14] - m[9]*m[6]*m[15] + m[9]*m[7]*m[14] + m[13]*m[6]*m[11] - m[13]*m[7]*m[10];
    inv[4]  = -m[4]*m[10]*m[15] + m[4]*m[11]*m[14] + m[8]*m[6]*m[15] - m[8]*m[7]*m[14] - m[12]*m[6]*m[11] + m[12]*m[7]*m[10];
    inv[8]  =  m[4]*m[9]*m[15]  - m[4]*m[11]*m[13] - m[8]*m[5]*m[15] + m[8]*m[7]*m[13] + m[12]*m[5]*m[11] - m[12]*m[7]*m[9];
    inv[12] = -m[4]*m[9]*m[14]  + m[4]*m[10]*m[13] + m[8]*m[5]*m[14] - m[8]*m[6]*m[13] - m[12]*m[5]*m[10] + m[12]*m[6]*m[9];
    inv[1]  = -m[1]*m[10]*m[15] + m[1]*m[11]*m[14] + m[9]*m[2]*m[15] - m[9]*m[3]*m[14] - m[13]*m[2]*m[11] + m[13]*m[3]*m[10];
    inv[5]  =  m[0]*m[10]*m[15] - m[0]*m[11]*m[14] - m[8]*m[2]*m[15] + m[8]*m[3]*m[14] + m[12]*m[2]*m[11] - m[12]*m[3]*m[10];
    inv[9]  = -m[0]*m[9]*m[15]  + m[0]*m[11]*m[13] + m[8]*m[1]*m[15] - m[8]*m[3]*m[13] - m[12]*m[1]*m[11] + m[12]*m[3]*m[9];
    inv[13] =  m[0]*m[9]*m[14]  - m[0]*m[10]*m[13] - m[8]*m[1]*m[14] + m[8]*m[2]*m[13] + m[12]*m[1]*m[10] - m[12]*m[2]*m[9];
    inv[2]  =  m[1]*m[6]*m[15]  - m[1]*m[7]*m[14]  - m[5]*m[2]*m[15] + m[5]*m[3]*m[14] + m[13]*m[2]*m[7]  - m[13]*m[3]*m[6];
    inv[6]  = -m[0]*m[6]*m[15]  + m[0]*m[7]*m[14]  + m[4]*m[2]*m[15] - m[4]*m[3]*m[14] - m[12]*m[2]*m[7]  + m[12]*m[3]*m[6];
    inv[10] =  m[0]*m[5]*m[15]  - m[0]*m[7]*m[13]  - m[4]*m[1]*m[15] + m[4]*m[3]*m[13] + m[12]*m[1]*m[7]  - m[12]*m[3]*m[5];
    inv[14] = -m[0]*m[5]*m[14]  + m[0]*m[6]*m[13]  + m[4]*m[1]*m[14] - m[4]*m[2]*m[13] - m[12]*m[1]*m[6]  + m[12]*m[2]*m[5];
    inv[3]  = -m[1]*m[6]*m[11]  + m[1]*m[7]*m[10]  + m[5]*m[2]*m[11] - m[5]*m[3]*m[10] - m[9]*m[2]*m[7]   + m[9]*m[3]*m[6];
    inv[7]  =  m[0]*m[6]*m[11]  - m[0]*m[7]*m[10]  - m[4]*m[2]*m[11] + m[4]*m[3]*m[10] + m[8]*m[2]*m[7]   - m[8]*m[3]*m[6];
    inv[11] = -m[0]*m[5]*m[11]  + m[0]*m[7]*m[9]   + m[4]*m[1]*m[11] - m[4]*m[3]*m[9]  - m[8]*m[1]*m[7]   + m[8]*m[3]*m[5];
    inv[15] =  m[0]*m[5]*m[10]  - m[0]*m[6]*m[9]   - m[4]*m[1]*m[10] + m[4]*m[2]*m[9]  + m[8]*m[1]*m[6]   - m[8]*m[2]*m[5];
    float det = m[0]*inv[0] + m[1]*inv[4] + m[2]*inv[8] + m[3]*inv[12];
    float idet = 1.0f / det;
    for (int i = 0; i < 16; i++) o[i] = inv[i] * idet;
}

__device__ void mul4(const float* A, const float* B, float* C) {
    for (int i = 0; i < 4; i++)
        for (int j = 0; j < 4; j++) {
            float s = 0.0f;
            for (int k = 0; k < 4; k++) s += A[4*i+k] * B[4*k+j];
            C[4*i+j] = s;
        }
}

__global__ __launch_bounds__(128) void render_k(
    const float* __restrict__ pixels,
    const float* __restrict__ Cm, const float* __restrict__ Wm, const float* __restrict__ Sm,
    const float* __restrict__ W1, const float* __restrict__ b1,
    const float* __restrict__ W2, const float* __restrict__ b2,
    const float* __restrict__ Wc1, const float* __restrict__ bc1,
    const float* __restrict__ Wc2, const float* __restrict__ bc2,
    float* __restrict__ out)
{
    const int r   = blockIdx.x;
    const int tid = threadIdx.x;

    __shared__ float sW1[3][H_], sb1[H_], sW2[H_];
    __shared__ float sWc1[6][H_], sbc1[H_], sWc2[H_][3];
    __shared__ float sval[RS];
    __shared__ float salpha[FULL_];
    __shared__ float srgb[FULL_][3];
    __shared__ float sgeo[7];     // cam0.xyz, ray.xyz, d_far
    __shared__ float ssec[5];     // d_pred, d_l, f_l, d_h, f_h
    __shared__ float sred[2];
    __shared__ float sdepth[2];   // dnp, dfp
    __shared__ int   sflags[2];

    // ---- stage weights into LDS (tid indexes hidden unit) ----
    sW1[0][tid] = W1[tid];
    sW1[1][tid] = W1[H_ + tid];
    sW1[2][tid] = W1[2*H_ + tid];
    sb1[tid] = b1[tid];
    sW2[tid] = W2[tid];
#pragma unroll
    for (int k = 0; k < 6; k++) sWc1[k][tid] = Wc1[k*H_ + tid];
    sbc1[tid] = bc1[tid];
    sWc2[tid][0] = Wc2[tid*3 + 0];
    sWc2[tid][1] = Wc2[tid*3 + 1];
    sWc2[tid][2] = Wc2[tid*3 + 2];
    const float b2v  = b2[0];
    const float bc20 = bc2[0], bc21 = bc2[1], bc22 = bc2[2];

    // ---- ray setup (thread 0) ----
    if (tid == 0) {
        float iC[16], iW[16], iS[16], T[16], M[16];
        inv4(Cm, iC); inv4(Wm, iW); inv4(Sm, iS);
        mul4(iW, iC, T);      // inv(world) @ inv(camera)
        mul4(iS, T, M);       // inv(scale) @ inv(world) @ inv(camera)
        float px = pixels[2*r], py = pixels[2*r + 1];
        float cam[3], dir[3];
        for (int i = 0; i < 3; i++) {
            cam[i] = M[4*i + 3];
            float pw = M[4*i + 0]*px + M[4*i + 1]*py + M[4*i + 2] + M[4*i + 3];
            dir[i] = pw - cam[i];
        }
        float nrm = sqrtf(dir[0]*dir[0] + dir[1]*dir[1] + dir[2]*dir[2]);
        float ray[3] = { dir[0]/nrm, dir[1]/nrm, dir[2]/nrm };
        float rcd = ray[0]*cam[0] + ray[1]*cam[1] + ray[2]*cam[2];
        float cc  = cam[0]*cam[0] + cam[1]*cam[1] + cam[2]*cam[2];
        float under = rcd*rcd - (cc - 1.0f);     // RADIUS = 1
        int   mint = under > 0.0f;
        float s = sqrtf(mint ? under : 1.0f);
        float dfar = mint ? fmaxf(s - rcd, 0.0f) : 0.0f;
        sgeo[0]=cam[0]; sgeo[1]=cam[1]; sgeo[2]=cam[2];
        sgeo[3]=ray[0]; sgeo[4]=ray[1]; sgeo[5]=ray[2];
        sgeo[6]=dfar;
        sflags[0]=mint;
    }
    __syncthreads();
    const float cx=sgeo[0], cy=sgeo[1], cz=sgeo[2];
    const float rx=sgeo[3], ry=sgeo[4], rz=sgeo[5];
    const float dfar=sgeo[6];
    const int   mask_int = sflags[0];

    // ---- phase 1: ray-march occupancy, one step per thread ----
    {
        float t = (float)tid * (1.0f / (RS - 1));
        float d = dfar * t;
        float px = cx + rx*d, py = cy + ry*d, pz = cz + rz*d;
        float acc = 0.0f;
#pragma unroll 4
        for (int j = 0; j < H_; j++) {
            float z = fmaf(px, sW1[0][j], fmaf(py, sW1[1][j], fmaf(pz, sW1[2][j], sb1[j])));
            acc = fmaf(softplus_f(z), sW2[j], acc);
        }
        sval[tid] = sigmoid_f(acc + b2v) - TAU_;
    }
    __syncthreads();

    // ---- phase 2: crossing detection (thread 0, literal argmin emulation) ----
    if (tid == 0) {
        int mask_0_free = sval[0] < 0.0f;
        float mincost = 1e30f; int ind = 0;
        for (int i = 0; i < RS; i++) {
            float c;
            if (i < RS - 1) {
                float pr = sval[i] * sval[i+1];
                float sg = (pr > 0.0f) ? 1.0f : ((pr < 0.0f) ? -1.0f : 0.0f);
                c = sg * (float)(RS - i);
            } else {
                c = 1.0f;
            }
            if (c < mincost) { mincost = c; ind = i; }
        }
        int mask_sc = mincost < 0.0f;
        float f_low = sval[ind];
        int ind_hi = min(ind + 1, RS - 1);
        float d_low  = dfar * ((float)ind    * (1.0f / (RS - 1)));
        float d_high = dfar * ((float)ind_hi * (1.0f / (RS - 1)));
        float f_high = sval[ind_hi];
        int mask = mask_sc && (f_low < 0.0f) && mask_int && mask_0_free;
        ssec[0] = secant_step(f_low, f_high, d_low, d_high);
        ssec[1] = d_low; ssec[2] = f_low; ssec[3] = d_high; ssec[4] = f_high;
        sflags[0] = mask;
        sflags[1] = mask_0_free;
    }
    __syncthreads();
    const int mask        = sflags[0];
    const int mask_0_free = sflags[1];

    // ---- secant refinement: 8 iters, H parallel over threads ----
    if (mask) {   // block-uniform branch
        for (int it = 0; it < NSEC; it++) {
            float d_p = ssec[0];
            float px = cx + rx*d_p, py = cy + ry*d_p, pz = cz + rz*d_p;
            float z = fmaf(px, sW1[0][tid], fmaf(py, sW1[1][tid], fmaf(pz, sW1[2][tid], sb1[tid])));
            float part = softplus_f(z) * sW2[tid];
#pragma unroll
            for (int off = 32; off; off >>= 1) part += __shfl_down(part, off, 64);
            if ((tid & 63) == 0) sred[tid >> 6] = part;
            __syncthreads();
            if (tid == 0) {
                float fm = sigmoid_f(sred[0] + sred[1] + b2v) - TAU_;
                float d_l = ssec[1], f_l = ssec[2], d_h = ssec[3], f_h = ssec[4];
                if (fm < 0.0f) { d_l = d_p; f_l = fm; }
                else           { d_h = d_p; f_h = fm; }
                ssec[1] = d_l; ssec[2] = f_l; ssec[3] = d_h; ssec[4] = f_h;
                ssec[0] = secant_step(f_l, f_h, d_l, d_h);
            }
            __syncthreads();
        }
    }

    // ---- depth interval selection (thread 0) ----
    if (tid == 0) {
        float d_i;
        if (!mask_0_free)      d_i = 0.0f;
        else if (mask)         d_i = ssec[0];
        else                   d_i = INFINITY;
        int mask_zero = (d_i == 0.0f);
        int mask_pred = isfinite(d_i);
        float dists = mask_pred ? d_i : 1.0f;
        if (mask_zero) dists = 0.0f;
        int obj = mask_pred && !mask_zero;
        sdepth[0] = fmaxf(dists - DELTA_, 0.0f);        // dnp (DEPTH_NEAR = 0)
        sdepth[1] = fminf(dists + DELTA_, dfar);        // dfp (d_surf = dfar)
        sflags[0] = obj;
    }
    __syncthreads();
    const int obj = sflags[0];

    // ---- phase 3: shading, one sample per thread (96 active) ----
    if (tid < FULL_) {
        float d;
        if (obj) {
            if (tid < SOUT_) {
                d = sdepth[0] * ((float)tid * (1.0f / (SOUT_ - 1)));
            } else {
                float u = (float)(tid - SOUT_) * (1.0f / (SIN_ - 1));
                d = sdepth[0] * (1.0f - u) + sdepth[1] * u;
            }
        } else {
            d = dfar * ((float)tid * (1.0f / (FULL_ - 1)));
        }
        float px = cx + rx*d, py = cy + ry*d, pz = cz + rz*d;
        float vx = -rx, vy = -ry, vz = -rz;
        float accA = 0.0f, a0 = 0.0f, a1 = 0.0f, a2 = 0.0f;
#pragma unroll 4
        for (int j = 0; j < H_; j++) {
            float z = fmaf(px, sW1[0][j], fmaf(py, sW1[1][j], fmaf(pz, sW1[2][j], sb1[j])));
            accA = fmaf(softplus_f(z), sW2[j], accA);
            float f = fmaf(px, sWc1[0][j], fmaf(py, sWc1[1][j], fmaf(pz, sWc1[2][j],
                      fmaf(vx, sWc1[3][j], fmaf(vy, sWc1[4][j], fmaf(vz, sWc1[5][j], sbc1[j]))))));
            f = fmaxf(f, 0.0f);
            a0 = fmaf(f, sWc2[j][0], a0);
            a1 = fmaf(f, sWc2[j][1], a1);
            a2 = fmaf(f, sWc2[j][2], a2);
        }
        salpha[tid]   = sigmoid_f(accA + b2v);   // occ + tau == sigmoid
        srgb[tid][0]  = sigmoid_f(a0 + bc20);
        srgb[tid][1]  = sigmoid_f(a1 + bc21);
        srgb[tid][2]  = sigmoid_f(a2 + bc22);
    }
    __syncthreads();

    // ---- alpha compositing (thread 0, 96 serial steps) ----
    if (tid == 0) {
        float T = 1.0f, o0 = 0.0f, o1 = 0.0f, o2 = 0.0f;
        for (int k = 0; k < FULL_; k++) {
            float a = salpha[k];
            float w = a * T;
            o0 = fmaf(w, srgb[k][0], o0);
            o1 = fmaf(w, srgb[k][1], o1);
            o2 = fmaf(w, srgb[k][2], o2);
            T *= (1.0f - a + EPSA);
        }
        out[3*r + 0] = o0;
        out[3*r + 1] = o1;
        out[3*r + 2] = o2;
    }
}

} // namespace

extern "C" void kernel_launch(void* const* d_in, const int* in_sizes, int n_in,
                              void* d_out, int out_size, void* d_ws, size_t ws_size,
                              hipStream_t stream) {
    const float* pixels = (const float*)d_in[0];
    const float* Cm  = (const float*)d_in[1];
    const float* Wm  = (const float*)d_in[2];
    const float* Sm  = (const float*)d_in[3];
    const float* W1  = (const float*)d_in[4];
    const float* b1  = (const float*)d_in[5];
    const float* W2  = (const float*)d_in[6];
    const float* b2  = (const float*)d_in[7];
    const float* Wc1 = (const float*)d_in[8];
    const float* bc1 = (const float*)d_in[9];
    const float* Wc2 = (const float*)d_in[10];
    const float* bc2 = (const float*)d_in[11];
    float* out = (float*)d_out;

    const int N = in_sizes[0] / 2;   // pixels is (B=1, N, 2)
    hipLaunchKernelGGL(render_k, dim3(N), dim3(128), 0, stream,
                       pixels, Cm, Wm, Sm, W1, b1, W2, b2, Wc1, bc1, Wc2, bc2, out);
}

// Round 2
// 180.448 us; speedup vs baseline: 3.1952x; 3.1952x over previous
//
#include <hip/hip_runtime.h>
#include <math.h>

// Renderer: occupancy-field ray marching + secant + shading, 1 block per ray.
// N=4096 rays, H=128 hidden, 128 ray steps, 8 secant iters, 96 shading samples.
// R2: native-exp/log softplus, float4-packed LDS weights, parallel argmin scan,
//     shuffle-scan compositing, geometry hoisted to a pre-kernel (d_ws).

namespace {

constexpr int H_    = 128;
constexpr int RS    = 128;   // RAY_STEPS
constexpr int NSEC  = 8;
constexpr int SOUT_ = 32;    // STEPS_OUT
constexpr int SIN_  = 64;    // STEPS_IN
constexpr int FULL_ = 96;
constexpr float EPSA   = 1e-6f;
constexpr float DELTA_ = 0.44626032029685964f; // max(2*exp(-1.5), 0.1)

// native-pipe softplus: max(x,0) + ln(1+e^{-|x|}); v_exp_f32/v_log_f32 based
__device__ __forceinline__ float softplus_fast(float x) {
    float e = __expf(-fabsf(x));          // native: mul + v_exp_f32
    float l = __logf(1.0f + e);           // native: v_log_f32 + mul
    return fmaxf(x, 0.0f) + l;
}
__device__ __forceinline__ float sigmoid_fast(float x) {
    return __builtin_amdgcn_rcpf(1.0f + __expf(-x));
}
__device__ __forceinline__ float secant_step(float f_l, float f_h, float d_l, float d_h) {
    float den = f_h - f_l;
    if (fabsf(den) > 1e-12f) return -f_l * (d_h - d_l) / den + d_l;
    return 0.5f * (d_l + d_h);
}

__device__ void inv4(const float* m, float* o) {
    float inv[16];
    inv[0]  =  m[5]*m[10]*m[15] - m[5]*m[11]*m[14] - m[9]*m[6]*m[15] + m[9]*m[7]*m[14] + m[13]*m[6]*m[11] - m[13]*m[7]*m[10];
    inv[4]  = -m[4]*m[10]*m[15] + m[4]*m[11]*m[14] + m[8]*m[6]*m[15] - m[8]*m[7]*m[14] - m[12]*m[6]*m[11] + m[12]*m[7]*m[10];
    inv[8]  =  m[4]*m[9]*m[15]  - m[4]*m[11]*m[13] - m[8]*m[5]*m[15] + m[8]*m[7]*m[13] + m[12]*m[5]*m[11] - m[12]*m[7]*m[9];
    inv[12] = -m[4]*m[9]*m[14]  + m[4]*m[10]*m[13] + m[8]*m[5]*m[14] - m[8]*m[6]*m[13] - m[12]*m[5]*m[10] + m[12]*m[6]*m[9];
    inv[1]  = -m[1]*m[10]*m[15] + m[1]*m[11]*m[14] + m[9]*m[2]*m[15] - m[9]*m[3]*m[14] - m[13]*m[2]*m[11] + m[13]*m[3]*m[10];
    inv[5]  =  m[0]*m[10]*m[15] - m[0]*m[11]*m[14] - m[8]*m[2]*m[15] + m[8]*m[3]*m[14] + m[12]*m[2]*m[11] - m[12]*m[3]*m[10];
    inv[9]  = -m[0]*m[9]*m[15]  + m[0]*m[11]*m[13] + m[8]*m[1]*m[15] - m[8]*m[3]*m[13] - m[12]*m[1]*m[11] + m[12]*m[3]*m[9];
    inv[13] =  m[0]*m[9]*m[14]  - m[0]*m[10]*m[13] - m[8]*m[1]*m[14] + m[8]*m[2]*m[13] + m[12]*m[1]*m[10] - m[12]*m[2]*m[9];
    inv[2]  =  m[1]*m[6]*m[15]  - m[1]*m[7]*m[14]  - m[5]*m[2]*m[15] + m[5]*m[3]*m[14] + m[13]*m[2]*m[7]  - m[13]*m[3]*m[6];
    inv[6]  = -m[0]*m[6]*m[15]  + m[0]*m[7]*m[14]  + m[4]*m[2]*m[15] - m[4]*m[3]*m[14] - m[12]*m[2]*m[7]  + m[12]*m[3]*m[6];
    inv[10] =  m[0]*m[5]*m[15]  - m[0]*m[7]*m[13]  - m[4]*m[1]*m[15] + m[4]*m[3]*m[13] + m[12]*m[1]*m[7]  - m[12]*m[3]*m[5];
    inv[14] = -m[0]*m[5]*m[14]  + m[0]*m[6]*m[13]  + m[4]*m[1]*m[14] - m[4]*m[2]*m[13] - m[12]*m[1]*m[6]  + m[12]*m[2]*m[5];
    inv[3]  = -m[1]*m[6]*m[11]  + m[1]*m[7]*m[10]  + m[5]*m[2]*m[11] - m[5]*m[3]*m[10] - m[9]*m[2]*m[7]   + m[9]*m[3]*m[6];
    inv[7]  =  m[0]*m[6]*m[11]  - m[0]*m[7]*m[10]  - m[4]*m[2]*m[11] + m[4]*m[3]*m[10] + m[8]*m[2]*m[7]   - m[8]*m[3]*m[6];
    inv[11] = -m[0]*m[5]*m[11]  + m[0]*m[7]*m[9]   + m[4]*m[1]*m[11] - m[4]*m[3]*m[9]  - m[8]*m[1]*m[7]   + m[8]*m[3]*m[5];
    inv[15] =  m[0]*m[5]*m[10]  - m[0]*m[6]*m[9]   - m[4]*m[1]*m[10] + m[4]*m[2]*m[9]  + m[8]*m[1]*m[6]   - m[8]*m[2]*m[5];
    float det = m[0]*inv[0] + m[1]*inv[4] + m[2]*inv[8] + m[3]*inv[12];
    float idet = 1.0f / det;
    for (int i = 0; i < 16; i++) o[i] = inv[i] * idet;
}

__device__ void mul4(const float* A, const float* B, float* C) {
    for (int i = 0; i < 4; i++)
        for (int j = 0; j < 4; j++) {
            float s = 0.0f;
            for (int k = 0; k < 4; k++) s += A[4*i+k] * B[4*k+j];
            C[4*i+j] = s;
        }
}

__device__ __forceinline__ void ray_setup(const float* M, float px_, float py_,
                                          float* cam, float* ray, float* dfar, int* mint) {
    float dir[3];
    for (int i = 0; i < 3; i++) {
        cam[i] = M[4*i + 3];
        float pw = M[4*i + 0]*px_ + M[4*i + 1]*py_ + M[4*i + 2] + M[4*i + 3];
        dir[i] = pw - cam[i];
    }
    float nrm = sqrtf(dir[0]*dir[0] + dir[1]*dir[1] + dir[2]*dir[2]);
    ray[0] = dir[0]/nrm; ray[1] = dir[1]/nrm; ray[2] = dir[2]/nrm;
    float rcd = ray[0]*cam[0] + ray[1]*cam[1] + ray[2]*cam[2];
    float cc  = cam[0]*cam[0] + cam[1]*cam[1] + cam[2]*cam[2];
    float under = rcd*rcd - (cc - 1.0f);
    *mint = under > 0.0f;
    float s = sqrtf(*mint ? under : 1.0f);
    *dfar = *mint ? fmaxf(s - rcd, 0.0f) : 0.0f;
}

// pre-kernel: per-ray geometry into gw[8*r] = {cam.xyz, ray.xyz, dfar, mint}
__global__ __launch_bounds__(256) void geo_k(
    const float* __restrict__ pixels,
    const float* __restrict__ Cm, const float* __restrict__ Wm, const float* __restrict__ Sm,
    float* __restrict__ gw, int N)
{
    int r = blockIdx.x * blockDim.x + threadIdx.x;
    if (r >= N) return;
    float iC[16], iW[16], iS[16], T[16], M[16];
    inv4(Cm, iC); inv4(Wm, iW); inv4(Sm, iS);
    mul4(iW, iC, T); mul4(iS, T, M);
    float cam[3], ray[3], dfar; int mint;
    ray_setup(M, pixels[2*r], pixels[2*r+1], cam, ray, &dfar, &mint);
    float* g = gw + 8*(size_t)r;
    g[0]=cam[0]; g[1]=cam[1]; g[2]=cam[2];
    g[3]=ray[0]; g[4]=ray[1]; g[5]=ray[2];
    g[6]=dfar;   g[7]=(float)mint;
}

__global__ __launch_bounds__(128) void render_k(
    const float* __restrict__ pixels,
    const float* __restrict__ Cm, const float* __restrict__ Wm, const float* __restrict__ Sm,
    const float* __restrict__ W1, const float* __restrict__ b1,
    const float* __restrict__ W2, const float* __restrict__ b2,
    const float* __restrict__ Wc1, const float* __restrict__ bc1,
    const float* __restrict__ Wc2, const float* __restrict__ bc2,
    const float* __restrict__ gw,   // may be null -> compute geometry inline
    float* __restrict__ out)
{
    const int r    = blockIdx.x;
    const int tid  = threadIdx.x;
    const int lane = tid & 63;
    const int wid  = tid >> 6;

    __shared__ float4 sG[H_];     // {W1_0, W1_1, W1_2, b1}
    __shared__ float  sW2[H_];
    __shared__ float4 sC1a[H_];   // {Wc1_0..3}
    __shared__ float4 sC1b[H_];   // {Wc1_4, Wc1_5, bc1, Wc2_0}
    __shared__ float2 sC2[H_];    // {Wc2_1, Wc2_2}
    __shared__ float  sval[RS];
    __shared__ float  sgeo[8];
    __shared__ float  ssec[5];    // d_pred, d_l, f_l, d_h, f_h
    __shared__ float  sredf[6];   // wave partial sums / argmin costs
    __shared__ int    sredi[2];
    __shared__ float  sscan[1];   // wave0 cumprod total
    __shared__ float  sdepth[2];  // dnp, dfp
    __shared__ int    sflags[2];

    // ---- stage weights into LDS (tid = hidden unit) ----
    sG[tid]  = make_float4(W1[tid], W1[H_ + tid], W1[2*H_ + tid], b1[tid]);
    sW2[tid] = W2[tid];
    sC1a[tid] = make_float4(Wc1[tid], Wc1[H_ + tid], Wc1[2*H_ + tid], Wc1[3*H_ + tid]);
    sC1b[tid] = make_float4(Wc1[4*H_ + tid], Wc1[5*H_ + tid], bc1[tid], Wc2[tid*3 + 0]);
    sC2[tid]  = make_float2(Wc2[tid*3 + 1], Wc2[tid*3 + 2]);
    const float b2v  = b2[0];
    const float bc20 = bc2[0], bc21 = bc2[1], bc22 = bc2[2];

    // ---- geometry ----
    float cx, cy, cz, rx, ry, rz, dfar;
    int mask_int;
    if (gw != nullptr) {
        const float* g = gw + 8*(size_t)r;
        cx = g[0]; cy = g[1]; cz = g[2];
        rx = g[3]; ry = g[4]; rz = g[5];
        dfar = g[6]; mask_int = g[7] != 0.0f;
        __syncthreads();   // weights staged
    } else {
        if (tid == 0) {
            float iC[16], iW[16], iS[16], T[16], M[16];
            inv4(Cm, iC); inv4(Wm, iW); inv4(Sm, iS);
            mul4(iW, iC, T); mul4(iS, T, M);
            float cam[3], ray[3], df; int mint;
            ray_setup(M, pixels[2*r], pixels[2*r+1], cam, ray, &df, &mint);
            sgeo[0]=cam[0]; sgeo[1]=cam[1]; sgeo[2]=cam[2];
            sgeo[3]=ray[0]; sgeo[4]=ray[1]; sgeo[5]=ray[2];
            sgeo[6]=df; sgeo[7]=(float)mint;
        }
        __syncthreads();
        cx=sgeo[0]; cy=sgeo[1]; cz=sgeo[2];
        rx=sgeo[3]; ry=sgeo[4]; rz=sgeo[5];
        dfar=sgeo[6]; mask_int = sgeo[7] != 0.0f;
    }

    // ---- phase 1: ray-march occupancy, one step per thread ----
    {
        float t = (float)tid * (1.0f / (RS - 1));
        float d = dfar * t;
        float px = cx + rx*d, py = cy + ry*d, pz = cz + rz*d;
        float acc0 = 0.0f, acc1 = 0.0f;
#pragma unroll 4
        for (int j = 0; j < H_; j += 2) {
            float4 g0 = sG[j];
            float4 g1 = sG[j+1];
            float z0 = fmaf(px, g0.x, fmaf(py, g0.y, fmaf(pz, g0.z, g0.w)));
            float z1 = fmaf(px, g1.x, fmaf(py, g1.y, fmaf(pz, g1.z, g1.w)));
            acc0 = fmaf(softplus_fast(z0), sW2[j],   acc0);
            acc1 = fmaf(softplus_fast(z1), sW2[j+1], acc1);
        }
        sval[tid] = sigmoid_fast(acc0 + acc1 + b2v) - 0.5f;
    }
    __syncthreads();

    // ---- phase 2: crossing detection, parallel argmin (first-min tiebreak) ----
    {
        float vi = sval[tid];
        float c;
        if (tid < RS - 1) {
            float pr = vi * sval[tid + 1];
            float sg = (pr > 0.0f) ? 1.0f : ((pr < 0.0f) ? -1.0f : 0.0f);
            c = sg * (float)(RS - tid);
        } else {
            c = 1.0f;   // sign=1, weight RS-127 = 1
        }
        int idx = tid;
#pragma unroll
        for (int off = 32; off; off >>= 1) {
            float c2 = __shfl_down(c, off, 64);
            int   i2 = __shfl_down(idx, off, 64);
            if (c2 < c || (c2 == c && i2 < idx)) { c = c2; idx = i2; }
        }
        if (lane == 0) { sredf[wid] = c; sredi[wid] = idx; }
    }
    __syncthreads();
    if (tid == 0) {
        float c0 = sredf[0], c1 = sredf[1];
        int   i0 = sredi[0], i1 = sredi[1];
        float cmin; int ind;
        if (c1 < c0 || (c1 == c0 && i1 < i0)) { cmin = c1; ind = i1; }
        else                                   { cmin = c0; ind = i0; }
        int mask_0_free = sval[0] < 0.0f;
        int mask_sc = cmin < 0.0f;
        float f_low = sval[ind];
        int ind_hi = min(ind + 1, RS - 1);
        float d_low  = dfar * ((float)ind    * (1.0f / (RS - 1)));
        float d_high = dfar * ((float)ind_hi * (1.0f / (RS - 1)));
        float f_high = sval[ind_hi];
        int mask = mask_sc && (f_low < 0.0f) && mask_int && mask_0_free;
        ssec[0] = secant_step(f_low, f_high, d_low, d_high);
        ssec[1] = d_low; ssec[2] = f_low; ssec[3] = d_high; ssec[4] = f_high;
        sflags[0] = mask;
        sflags[1] = mask_0_free;
    }
    __syncthreads();
    const int mask        = sflags[0];
    const int mask_0_free = sflags[1];

    // ---- secant refinement: 8 iters, H parallel over threads ----
    if (mask) {   // block-uniform branch
        const float4 gt  = sG[tid];
        const float  w2t = sW2[tid];
        for (int it = 0; it < NSEC; it++) {
            float d_p = ssec[0];
            float px = cx + rx*d_p, py = cy + ry*d_p, pz = cz + rz*d_p;
            float z = fmaf(px, gt.x, fmaf(py, gt.y, fmaf(pz, gt.z, gt.w)));
            float part = softplus_fast(z) * w2t;
#pragma unroll
            for (int off = 32; off; off >>= 1) part += __shfl_down(part, off, 64);
            if (lane == 0) sredf[wid] = part;
            __syncthreads();
            if (tid == 0) {
                float fm = sigmoid_fast(sredf[0] + sredf[1] + b2v) - 0.5f;
                float d_l = ssec[1], f_l = ssec[2], d_h = ssec[3], f_h = ssec[4];
                if (fm < 0.0f) { d_l = d_p; f_l = fm; }
                else           { d_h = d_p; f_h = fm; }
                ssec[1] = d_l; ssec[2] = f_l; ssec[3] = d_h; ssec[4] = f_h;
                ssec[0] = secant_step(f_l, f_h, d_l, d_h);
            }
            __syncthreads();
        }
    }

    // ---- depth interval selection (thread 0) ----
    if (tid == 0) {
        float d_i;
        if (!mask_0_free)      d_i = 0.0f;
        else if (mask)         d_i = ssec[0];
        else                   d_i = INFINITY;
        int mask_zero = (d_i == 0.0f);
        int mask_pred = isfinite(d_i);
        float dists = mask_pred ? d_i : 1.0f;
        if (mask_zero) dists = 0.0f;
        int obj = mask_pred && !mask_zero;
        sdepth[0] = fmaxf(dists - DELTA_, 0.0f);   // dnp (DEPTH_NEAR=0)
        sdepth[1] = fminf(dists + DELTA_, dfar);   // dfp (d_surf=dfar)
        sflags[0] = obj;
    }
    __syncthreads();
    const int obj = sflags[0];

    // ---- phase 3: shading, one sample per thread (96 active) ----
    float alpha = 0.0f, rgb0 = 0.0f, rgb1 = 0.0f, rgb2 = 0.0f;
    if (tid < FULL_) {
        float d;
        if (obj) {
            if (tid < SOUT_) {
                d = sdepth[0] * ((float)tid * (1.0f / (SOUT_ - 1)));
            } else {
                float u = (float)(tid - SOUT_) * (1.0f / (SIN_ - 1));
                d = sdepth[0] * (1.0f - u) + sdepth[1] * u;
            }
        } else {
            d = dfar * ((float)tid * (1.0f / (FULL_ - 1)));
        }
        float px = cx + rx*d, py = cy + ry*d, pz = cz + rz*d;
        float vx = -rx, vy = -ry, vz = -rz;
        float accA = 0.0f, a0 = 0.0f, a1 = 0.0f, a2 = 0.0f;
#pragma unroll 4
        for (int j = 0; j < H_; j++) {
            float4 g = sG[j];
            float z = fmaf(px, g.x, fmaf(py, g.y, fmaf(pz, g.z, g.w)));
            accA = fmaf(softplus_fast(z), sW2[j], accA);
            float4 ca = sC1a[j];
            float4 cb = sC1b[j];
            float2 c2 = sC2[j];
            float f = fmaf(px, ca.x, fmaf(py, ca.y, fmaf(pz, ca.z,
                      fmaf(vx, ca.w, fmaf(vy, cb.x, fmaf(vz, cb.y, cb.z))))));
            f = fmaxf(f, 0.0f);
            a0 = fmaf(f, cb.w, a0);
            a1 = fmaf(f, c2.x, a1);
            a2 = fmaf(f, c2.y, a2);
        }
        alpha = sigmoid_fast(accA + b2v);         // occ + tau == sigmoid
        rgb0  = sigmoid_fast(a0 + bc20);
        rgb1  = sigmoid_fast(a1 + bc21);
        rgb2  = sigmoid_fast(a2 + bc22);
    }

    // ---- alpha compositing: shuffle-scan cumprod + weighted reduction ----
    {
        float m = (tid < FULL_) ? (1.0f - alpha + EPSA) : 1.0f;
        float p = m;
#pragma unroll
        for (int off = 1; off < 64; off <<= 1) {
            float v = __shfl_up(p, off, 64);
            if (lane >= off) p *= v;
        }
        if (tid == 63) sscan[0] = p;      // wave0 total product
        __syncthreads();
        float excl = __shfl_up(p, 1, 64); // wave-local exclusive cumprod
        if (lane == 0) excl = 1.0f;
        float T = (wid == 0) ? excl : excl * sscan[0];
        float w = alpha * T;              // transmittance-weighted alpha
        float s0 = w * rgb0, s1 = w * rgb1, s2 = w * rgb2;
#pragma unroll
        for (int off = 32; off; off >>= 1) {
            s0 += __shfl_down(s0, off, 64);
            s1 += __shfl_down(s1, off, 64);
            s2 += __shfl_down(s2, off, 64);
        }
        if (lane == 0) { sredf[wid*3+0]=s0; sredf[wid*3+1]=s1; sredf[wid*3+2]=s2; }
        __syncthreads();
        if (tid == 0) {
            out[3*r + 0] = sredf[0] + sredf[3];
            out[3*r + 1] = sredf[1] + sredf[4];
            out[3*r + 2] = sredf[2] + sredf[5];
        }
    }
}

} // namespace

extern "C" void kernel_launch(void* const* d_in, const int* in_sizes, int n_in,
                              void* d_out, int out_size, void* d_ws, size_t ws_size,
                              hipStream_t stream) {
    const float* pixels = (const float*)d_in[0];
    const float* Cm  = (const float*)d_in[1];
    const float* Wm  = (const float*)d_in[2];
    const float* Sm  = (const float*)d_in[3];
    const float* W1  = (const float*)d_in[4];
    const float* b1  = (const float*)d_in[5];
    const float* W2  = (const float*)d_in[6];
    const float* b2  = (const float*)d_in[7];
    const float* Wc1 = (const float*)d_in[8];
    const float* bc1 = (const float*)d_in[9];
    const float* Wc2 = (const float*)d_in[10];
    const float* bc2 = (const float*)d_in[11];
    float* out = (float*)d_out;

    const int N = in_sizes[0] / 2;   // pixels is (B=1, N, 2)
    const size_t geo_bytes = (size_t)N * 8 * sizeof(float);
    float* gw = nullptr;
    if (ws_size >= geo_bytes) {
        gw = (float*)d_ws;
        hipLaunchKernelGGL(geo_k, dim3((N + 255) / 256), dim3(256), 0, stream,
                           pixels, Cm, Wm, Sm, gw, N);
    }
    hipLaunchKernelGGL(render_k, dim3(N), dim3(128), 0, stream,
                       pixels, Cm, Wm, Sm, W1, b1, W2, b2, Wc1, bc1, Wc2, bc2, gw, out);
}

// Round 3
// 168.617 us; speedup vs baseline: 3.4194x; 1.0702x over previous
//
#include <hip/hip_runtime.h>
#include <math.h>

// Renderer: occupancy-field ray marching + secant + shading.
// R3: 4 rays per 128-thread block (amortizes LDS weight reads over 4 samples
//     in phase 1 / 3 samples in phase 3), geometry inlined (single kernel),
//     secant fully register-resident with 32-lane butterfly reductions.

namespace {

constexpr int H_    = 128;
constexpr int RS    = 128;   // RAY_STEPS
constexpr int NSEC  = 8;
constexpr int SOUT_ = 32;    // STEPS_OUT
constexpr int SIN_  = 64;    // STEPS_IN
constexpr int FULL_ = 96;
constexpr int RPB   = 4;     // rays per block
constexpr float EPSA   = 1e-6f;
constexpr float DELTA_ = 0.44626032029685964f; // max(2*exp(-1.5), 0.1)

__device__ __forceinline__ float softplus_fast(float x) {
    float e = __expf(-fabsf(x));
    float l = __logf(1.0f + e);
    return fmaxf(x, 0.0f) + l;
}
__device__ __forceinline__ float sigmoid_fast(float x) {
    return __builtin_amdgcn_rcpf(1.0f + __expf(-x));
}
__device__ __forceinline__ float secant_step(float f_l, float f_h, float d_l, float d_h) {
    float den = f_h - f_l;
    if (fabsf(den) > 1e-12f) return -f_l * (d_h - d_l) / den + d_l;
    return 0.5f * (d_l + d_h);
}

__device__ void inv4(const float* m, float* o) {
    float inv[16];
    inv[0]  =  m[5]*m[10]*m[15] - m[5]*m[11]*m[14] - m[9]*m[6]*m[15] + m[9]*m[7]*m[14] + m[13]*m[6]*m[11] - m[13]*m[7]*m[10];
    inv[4]  = -m[4]*m[10]*m[15] + m[4]*m[11]*m[14] + m[8]*m[6]*m[15] - m[8]*m[7]*m[14] - m[12]*m[6]*m[11] + m[12]*m[7]*m[10];
    inv[8]  =  m[4]*m[9]*m[15]  - m[4]*m[11]*m[13] - m[8]*m[5]*m[15] + m[8]*m[7]*m[13] + m[12]*m[5]*m[11] - m[12]*m[7]*m[9];
    inv[12] = -m[4]*m[9]*m[14]  + m[4]*m[10]*m[13] + m[8]*m[5]*m[14] - m[8]*m[6]*m[13] - m[12]*m[5]*m[10] + m[12]*m[6]*m[9];
    inv[1]  = -m[1]*m[10]*m[15] + m[1]*m[11]*m[14] + m[9]*m[2]*m[15] - m[9]*m[3]*m[14] - m[13]*m[2]*m[11] + m[13]*m[3]*m[10];
    inv[5]  =  m[0]*m[10]*m[15] - m[0]*m[11]*m[14] - m[8]*m[2]*m[15] + m[8]*m[3]*m[14] + m[12]*m[2]*m[11] - m[12]*m[3]*m[10];
    inv[9]  = -m[0]*m[9]*m[15]  + m[0]*m[11]*m[13] + m[8]*m[1]*m[15] - m[8]*m[3]*m[13] - m[12]*m[1]*m[11] + m[12]*m[3]*m[9];
    inv[13] =  m[0]*m[9]*m[14]  - m[0]*m[10]*m[13] - m[8]*m[1]*m[14] + m[8]*m[2]*m[13] + m[12]*m[1]*m[10] - m[12]*m[2]*m[9];
    inv[2]  =  m[1]*m[6]*m[15]  - m[1]*m[7]*m[14]  - m[5]*m[2]*m[15] + m[5]*m[3]*m[14] + m[13]*m[2]*m[7]  - m[13]*m[3]*m[6];
    inv[6]  = -m[0]*m[6]*m[15]  + m[0]*m[7]*m[14]  + m[4]*m[2]*m[15] - m[4]*m[3]*m[14] - m[12]*m[2]*m[7]  + m[12]*m[3]*m[6];
    inv[10] =  m[0]*m[5]*m[15]  - m[0]*m[7]*m[13]  - m[4]*m[1]*m[15] + m[4]*m[3]*m[13] + m[12]*m[1]*m[7]  - m[12]*m[3]*m[5];
    inv[14] = -m[0]*m[5]*m[14]  + m[0]*m[6]*m[13]  + m[4]*m[1]*m[14] - m[4]*m[2]*m[13] - m[12]*m[1]*m[6]  + m[12]*m[2]*m[5];
    inv[3]  = -m[1]*m[6]*m[11]  + m[1]*m[7]*m[10]  + m[5]*m[2]*m[11] - m[5]*m[3]*m[10] - m[9]*m[2]*m[7]   + m[9]*m[3]*m[6];
    inv[7]  =  m[0]*m[6]*m[11]  - m[0]*m[7]*m[10]  - m[4]*m[2]*m[11] + m[4]*m[3]*m[10] + m[8]*m[2]*m[7]   - m[8]*m[3]*m[6];
    inv[11] = -m[0]*m[5]*m[11]  + m[0]*m[7]*m[9]   + m[4]*m[1]*m[11] - m[4]*m[3]*m[9]  - m[8]*m[1]*m[7]   + m[8]*m[3]*m[5];
    inv[15] =  m[0]*m[5]*m[10]  - m[0]*m[6]*m[9]   - m[4]*m[1]*m[10] + m[4]*m[2]*m[9]  + m[8]*m[1]*m[6]   - m[8]*m[2]*m[5];
    float det = m[0]*inv[0] + m[1]*inv[4] + m[2]*inv[8] + m[3]*inv[12];
    float idet = 1.0f / det;
    for (int i = 0; i < 16; i++) o[i] = inv[i] * idet;
}

__device__ void mul4(const float* A, const float* B, float* C) {
    for (int i = 0; i < 4; i++)
        for (int j = 0; j < 4; j++) {
            float s = 0.0f;
            for (int k = 0; k < 4; k++) s += A[4*i+k] * B[4*k+j];
            C[4*i+j] = s;
        }
}

__global__ __launch_bounds__(128) void render_k(
    const float* __restrict__ pixels,
    const float* __restrict__ Cm, const float* __restrict__ Wm, const float* __restrict__ Sm,
    const float* __restrict__ W1, const float* __restrict__ b1,
    const float* __restrict__ W2, const float* __restrict__ b2,
    const float* __restrict__ Wc1, const float* __restrict__ bc1,
    const float* __restrict__ Wc2, const float* __restrict__ bc2,
    float* __restrict__ out, int N)
{
    const int tid = threadIdx.x;
    const int r0  = blockIdx.x * RPB;

    __shared__ float4 sG[H_];     // {W1_0, W1_1, W1_2, b1}
    __shared__ float  sW2[H_];
    __shared__ float4 sC1a[H_];   // {Wc1_0..3}
    __shared__ float4 sC1b[H_];   // {Wc1_4, Wc1_5, bc1, Wc2_0}
    __shared__ float2 sC2[H_];    // {Wc2_1, Wc2_2}
    __shared__ __align__(16) float sval[RPB][RS];
    __shared__ float4 sPix[RPB][FULL_];   // {r,g,b,alpha}
    __shared__ float  sgeo[RPB][8];       // cam.xyz, ray.xyz, dfar, mint
    __shared__ float  sdep[RPB][2];       // dnp, dfp
    __shared__ int    sobj[RPB];

    // ---- stage weights into LDS (tid = hidden unit) ----
    sG[tid]   = make_float4(W1[tid], W1[H_ + tid], W1[2*H_ + tid], b1[tid]);
    sW2[tid]  = W2[tid];
    sC1a[tid] = make_float4(Wc1[tid], Wc1[H_ + tid], Wc1[2*H_ + tid], Wc1[3*H_ + tid]);
    sC1b[tid] = make_float4(Wc1[4*H_ + tid], Wc1[5*H_ + tid], bc1[tid], Wc2[tid*3 + 0]);
    sC2[tid]  = make_float2(Wc2[tid*3 + 1], Wc2[tid*3 + 2]);
    const float b2v  = b2[0];
    const float bc20 = bc2[0], bc21 = bc2[1], bc22 = bc2[2];

    // ---- geometry: lanes 0..3 each handle one ray ----
    if (tid < RPB) {
        const int r = r0 + tid;
        float cam[3] = {0,0,0}, ray[3] = {0,0,0};
        float dfar = 0.0f; int mint = 0;
        if (r < N) {
            float iC[16], iW[16], iS[16], T[16], M[16];
            inv4(Cm, iC); inv4(Wm, iW); inv4(Sm, iS);
            mul4(iW, iC, T); mul4(iS, T, M);
            float px_ = pixels[2*r], py_ = pixels[2*r + 1];
            float dir[3];
            for (int i = 0; i < 3; i++) {
                cam[i] = M[4*i + 3];
                float pw = M[4*i + 0]*px_ + M[4*i + 1]*py_ + M[4*i + 2] + M[4*i + 3];
                dir[i] = pw - cam[i];
            }
            float nrm = sqrtf(dir[0]*dir[0] + dir[1]*dir[1] + dir[2]*dir[2]);
            ray[0] = dir[0]/nrm; ray[1] = dir[1]/nrm; ray[2] = dir[2]/nrm;
            float rcd = ray[0]*cam[0] + ray[1]*cam[1] + ray[2]*cam[2];
            float cc  = cam[0]*cam[0] + cam[1]*cam[1] + cam[2]*cam[2];
            float under = rcd*rcd - (cc - 1.0f);
            mint = under > 0.0f;
            float s = sqrtf(mint ? under : 1.0f);
            dfar = mint ? fmaxf(s - rcd, 0.0f) : 0.0f;
        }
        sgeo[tid][0]=cam[0]; sgeo[tid][1]=cam[1]; sgeo[tid][2]=cam[2];
        sgeo[tid][3]=ray[0]; sgeo[tid][4]=ray[1]; sgeo[tid][5]=ray[2];
        sgeo[tid][6]=dfar;   sgeo[tid][7]=(float)mint;
    }
    __syncthreads();

    // ---- phase 1: ray-march occupancy; step = tid, 4 rays per thread ----
    {
        const float t = (float)tid * (1.0f / (RS - 1));
        float px[RPB], py[RPB], pz[RPB], acc[RPB];
#pragma unroll
        for (int g = 0; g < RPB; g++) {
            float d = sgeo[g][6] * t;
            px[g] = sgeo[g][0] + sgeo[g][3]*d;
            py[g] = sgeo[g][1] + sgeo[g][4]*d;
            pz[g] = sgeo[g][2] + sgeo[g][5]*d;
            acc[g] = 0.0f;
        }
#pragma unroll 4
        for (int j = 0; j < H_; j++) {
            float4 gw = sG[j];
            float  w2 = sW2[j];
#pragma unroll
            for (int g = 0; g < RPB; g++) {
                float z = fmaf(px[g], gw.x, fmaf(py[g], gw.y, fmaf(pz[g], gw.z, gw.w)));
                acc[g] = fmaf(softplus_fast(z), w2, acc[g]);
            }
        }
#pragma unroll
        for (int g = 0; g < RPB; g++)
            sval[g][tid] = sigmoid_fast(acc[g] + b2v) - 0.5f;
    }
    __syncthreads();

    // ---- phase 2 + secant: 32-lane group g = tid>>5 handles ray g ----
    {
        const int g = tid >> 5;
        const int l = tid & 31;
        // crossing-cost first-min over 128 steps (4 consecutive per lane)
        const float4* sv4 = (const float4*)&sval[g][0];
        float4 v = sv4[l];
        float nxt = (l < 31) ? sval[g][4*l + 4] : 0.0f;
        float vv[5] = {v.x, v.y, v.z, v.w, nxt};
        float cmin = 1e30f; int ind = 0;
#pragma unroll
        for (int k = 0; k < 4; k++) {
            int i = 4*l + k;
            float c;
            if (i < RS - 1) {
                float pr = vv[k] * vv[k+1];
                float sg = (pr > 0.0f) ? 1.0f : ((pr < 0.0f) ? -1.0f : 0.0f);
                c = sg * (float)(RS - i);
            } else {
                c = 1.0f;
            }
            if (c < cmin) { cmin = c; ind = i; }
        }
#pragma unroll
        for (int off = 16; off; off >>= 1) {
            float c2 = __shfl_xor(cmin, off, 32);
            int   i2 = __shfl_xor(ind,  off, 32);
            if (c2 < cmin || (c2 == cmin && i2 < ind)) { cmin = c2; ind = i2; }
        }
        const float dfar = sgeo[g][6];
        const int mask_0_free = sval[g][0] < 0.0f;
        const int mask_sc = cmin < 0.0f;
        const float f_low = sval[g][ind];
        const int ind_hi = min(ind + 1, RS - 1);
        const float d_low  = dfar * ((float)ind    * (1.0f / (RS - 1)));
        const float d_high = dfar * ((float)ind_hi * (1.0f / (RS - 1)));
        const float f_high = sval[g][ind_hi];
        const int msk = mask_sc && (f_low < 0.0f) && (sgeo[g][7] != 0.0f) && mask_0_free;

        float d_p = secant_step(f_low, f_high, d_low, d_high);
        if (msk) {   // uniform within the 32-lane group
            const float cx = sgeo[g][0], cy = sgeo[g][1], cz = sgeo[g][2];
            const float rx = sgeo[g][3], ry = sgeo[g][4], rz = sgeo[g][5];
            const float4 g0 = sG[l], g1 = sG[l+32], g2 = sG[l+64], g3 = sG[l+96];
            const float w20 = sW2[l], w21 = sW2[l+32], w22 = sW2[l+64], w23 = sW2[l+96];
            float d_l = d_low, f_l = f_low, d_h = d_high, f_h = f_high;
            for (int it = 0; it < NSEC; it++) {
                float px = cx + rx*d_p, py = cy + ry*d_p, pz = cz + rz*d_p;
                float z0 = fmaf(px, g0.x, fmaf(py, g0.y, fmaf(pz, g0.z, g0.w)));
                float z1 = fmaf(px, g1.x, fmaf(py, g1.y, fmaf(pz, g1.z, g1.w)));
                float z2 = fmaf(px, g2.x, fmaf(py, g2.y, fmaf(pz, g2.z, g2.w)));
                float z3 = fmaf(px, g3.x, fmaf(py, g3.y, fmaf(pz, g3.z, g3.w)));
                float part = softplus_fast(z0)*w20 + softplus_fast(z1)*w21
                           + softplus_fast(z2)*w22 + softplus_fast(z3)*w23;
#pragma unroll
                for (int off = 16; off; off >>= 1) part += __shfl_xor(part, off, 32);
                float fm = sigmoid_fast(part + b2v) - 0.5f;
                bool low = fm < 0.0f;
                d_l = low ? d_p : d_l;  f_l = low ? fm : f_l;
                d_h = low ? d_h : d_p;  f_h = low ? f_h : fm;
                d_p = secant_step(f_l, f_h, d_l, d_h);
            }
        }
        if (l == 0) {
            float d_i;
            if (!mask_0_free)      d_i = 0.0f;
            else if (msk)          d_i = d_p;
            else                   d_i = INFINITY;
            int mask_zero = (d_i == 0.0f);
            int mask_pred = isfinite(d_i);
            float dists = mask_pred ? d_i : 1.0f;
            if (mask_zero) dists = 0.0f;
            sobj[g]    = mask_pred && !mask_zero;
            sdep[g][0] = fmaxf(dists - DELTA_, 0.0f);   // dnp
            sdep[g][1] = fminf(dists + DELTA_, dfar);   // dfp
        }
    }
    __syncthreads();

    // ---- phase 3: shading; 384 samples on 128 threads (3 each) ----
    {
        float px3[3], py3[3], pz3[3], vx3[3], vy3[3], vz3[3];
        float accA[3], a0[3], a1[3], a2[3];
        int   gg[3], ss[3];
#pragma unroll
        for (int m = 0; m < 3; m++) {
            int idx = tid + 128*m;
            int g = (idx * 683) >> 16;      // idx / 96 for idx < 384
            int s = idx - 96*g;
            gg[m] = g; ss[m] = s;
            float d;
            if (sobj[g]) {
                if (s < SOUT_) {
                    d = sdep[g][0] * ((float)s * (1.0f / (SOUT_ - 1)));
                } else {
                    float u = (float)(s - SOUT_) * (1.0f / (SIN_ - 1));
                    d = sdep[g][0] * (1.0f - u) + sdep[g][1] * u;
                }
            } else {
                d = sgeo[g][6] * ((float)s * (1.0f / (FULL_ - 1)));
            }
            px3[m] = sgeo[g][0] + sgeo[g][3]*d;
            py3[m] = sgeo[g][1] + sgeo[g][4]*d;
            pz3[m] = sgeo[g][2] + sgeo[g][5]*d;
            vx3[m] = -sgeo[g][3]; vy3[m] = -sgeo[g][4]; vz3[m] = -sgeo[g][5];
            accA[m] = 0.0f; a0[m] = 0.0f; a1[m] = 0.0f; a2[m] = 0.0f;
        }
#pragma unroll 2
        for (int j = 0; j < H_; j++) {
            float4 gw = sG[j];
            float  w2 = sW2[j];
            float4 ca = sC1a[j];
            float4 cb = sC1b[j];
            float2 c2 = sC2[j];
#pragma unroll
            for (int m = 0; m < 3; m++) {
                float z = fmaf(px3[m], gw.x, fmaf(py3[m], gw.y, fmaf(pz3[m], gw.z, gw.w)));
                accA[m] = fmaf(softplus_fast(z), w2, accA[m]);
                float f = fmaf(px3[m], ca.x, fmaf(py3[m], ca.y, fmaf(pz3[m], ca.z,
                          fmaf(vx3[m], ca.w, fmaf(vy3[m], cb.x, fmaf(vz3[m], cb.y, cb.z))))));
                f = fmaxf(f, 0.0f);
                a0[m] = fmaf(f, cb.w, a0[m]);
                a1[m] = fmaf(f, c2.x, a1[m]);
                a2[m] = fmaf(f, c2.y, a2[m]);
            }
        }
#pragma unroll
        for (int m = 0; m < 3; m++) {
            float alpha = sigmoid_fast(accA[m] + b2v);
            sPix[gg[m]][ss[m]] = make_float4(sigmoid_fast(a0[m] + bc20),
                                             sigmoid_fast(a1[m] + bc21),
                                             sigmoid_fast(a2[m] + bc22),
                                             alpha);
        }
    }
    __syncthreads();

    // ---- alpha compositing: lanes 0..3, one ray each, 96 serial steps ----
    if (tid < RPB && r0 + tid < N) {
        float T = 1.0f, o0 = 0.0f, o1 = 0.0f, o2 = 0.0f;
        for (int k = 0; k < FULL_; k++) {
            float4 P = sPix[tid][k];
            float w = P.w * T;
            o0 = fmaf(w, P.x, o0);
            o1 = fmaf(w, P.y, o1);
            o2 = fmaf(w, P.z, o2);
            T *= (1.0f - P.w + EPSA);
        }
        const int r = r0 + tid;
        out[3*r + 0] = o0;
        out[3*r + 1] = o1;
        out[3*r + 2] = o2;
    }
}

} // namespace

extern "C" void kernel_launch(void* const* d_in, const int* in_sizes, int n_in,
                              void* d_out, int out_size, void* d_ws, size_t ws_size,
                              hipStream_t stream) {
    const float* pixels = (const float*)d_in[0];
    const float* Cm  = (const float*)d_in[1];
    const float* Wm  = (const float*)d_in[2];
    const float* Sm  = (const float*)d_in[3];
    const float* W1  = (const float*)d_in[4];
    const float* b1  = (const float*)d_in[5];
    const float* W2  = (const float*)d_in[6];
    const float* b2  = (const float*)d_in[7];
    const float* Wc1 = (const float*)d_in[8];
    const float* bc1 = (const float*)d_in[9];
    const float* Wc2 = (const float*)d_in[10];
    const float* bc2 = (const float*)d_in[11];
    float* out = (float*)d_out;

    const int N = in_sizes[0] / 2;   // pixels is (B=1, N, 2)
    const int blocks = (N + RPB - 1) / RPB;
    hipLaunchKernelGGL(render_k, dim3(blocks), dim3(128), 0, stream,
                       pixels, Cm, Wm, Sm, W1, b1, W2, b2, Wc1, bc1, Wc2, bc2, out, N);
}

// Round 4
// 153.097 us; speedup vs baseline: 3.7660x; 1.1014x over previous
//
#include <hip/hip_runtime.h>
#include <math.h>

// Renderer: occupancy-field ray marching + secant + shading.
// R4: RPB=2 (4 waves/SIMD), linear reparam z_j(d)=a_j*d+c_j for phase3/secant,
//     log2-domain softplus on continuous paths, phase 1 kept bitwise == R3
//     (feeds discrete decisions), logits stored (sigmoid applied at consumers).

namespace {

constexpr int H_    = 128;
constexpr int RS    = 128;   // RAY_STEPS
constexpr int NSEC  = 8;
constexpr int SOUT_ = 32;    // STEPS_OUT
constexpr int SIN_  = 64;    // STEPS_IN
constexpr int FULL_ = 96;
constexpr int RPB   = 2;     // rays per block
constexpr float EPSA   = 1e-6f;
constexpr float DELTA_ = 0.44626032029685964f; // max(2*exp(-1.5), 0.1)
constexpr float L2E    = 1.4426950408889634f;  // log2(e)
constexpr float LN2    = 0.6931471805599453f;

// ---- exact R3 helpers (discrete-critical paths must match R3 bitwise) ----
__device__ __forceinline__ float softplus_fast(float x) {
    float e = __expf(-fabsf(x));
    float l = __logf(1.0f + e);
    return fmaxf(x, 0.0f) + l;
}
__device__ __forceinline__ float sigmoid_fast(float x) {
    return __builtin_amdgcn_rcpf(1.0f + __expf(-x));
}
// log2-domain softplus (continuous paths only): input u = z*log2e,
// returns log2-units; multiply by w2*ln2 to get softplus(z)*w2.
__device__ __forceinline__ float sp2(float u) {
    float e = __builtin_amdgcn_exp2f(-fabsf(u));
    return fmaxf(u, 0.0f) + __builtin_amdgcn_logf(1.0f + e);  // v_log = log2
}
__device__ __forceinline__ float secant_step(float f_l, float f_h, float d_l, float d_h) {
    float den = f_h - f_l;
    if (fabsf(den) > 1e-12f) return -f_l * (d_h - d_l) / den + d_l;
    return 0.5f * (d_l + d_h);
}

__device__ void inv4(const float* m, float* o) {
    float inv[16];
    inv[0]  =  m[5]*m[10]*m[15] - m[5]*m[11]*m[14] - m[9]*m[6]*m[15] + m[9]*m[7]*m[14] + m[13]*m[6]*m[11] - m[13]*m[7]*m[10];
    inv[4]  = -m[4]*m[10]*m[15] + m[4]*m[11]*m[14] + m[8]*m[6]*m[15] - m[8]*m[7]*m[14] - m[12]*m[6]*m[11] + m[12]*m[7]*m[10];
    inv[8]  =  m[4]*m[9]*m[15]  - m[4]*m[11]*m[13] - m[8]*m[5]*m[15] + m[8]*m[7]*m[13] + m[12]*m[5]*m[11] - m[12]*m[7]*m[9];
    inv[12] = -m[4]*m[9]*m[14]  + m[4]*m[10]*m[13] + m[8]*m[5]*m[14] - m[8]*m[6]*m[13] - m[12]*m[5]*m[10] + m[12]*m[6]*m[9];
    inv[1]  = -m[1]*m[10]*m[15] + m[1]*m[11]*m[14] + m[9]*m[2]*m[15] - m[9]*m[3]*m[14] - m[13]*m[2]*m[11] + m[13]*m[3]*m[10];
    inv[5]  =  m[0]*m[10]*m[15] - m[0]*m[11]*m[14] - m[8]*m[2]*m[15] + m[8]*m[3]*m[14] + m[12]*m[2]*m[11] - m[12]*m[3]*m[10];
    inv[9]  = -m[0]*m[9]*m[15]  + m[0]*m[11]*m[13] + m[8]*m[1]*m[15] - m[8]*m[3]*m[13] - m[12]*m[1]*m[11] + m[12]*m[3]*m[9];
    inv[13] =  m[0]*m[9]*m[14]  - m[0]*m[10]*m[13] - m[8]*m[1]*m[14] + m[8]*m[2]*m[13] + m[12]*m[1]*m[10] - m[12]*m[2]*m[9];
    inv[2]  =  m[1]*m[6]*m[15]  - m[1]*m[7]*m[14]  - m[5]*m[2]*m[15] + m[5]*m[3]*m[14] + m[13]*m[2]*m[7]  - m[13]*m[3]*m[6];
    inv[6]  = -m[0]*m[6]*m[15]  + m[0]*m[7]*m[14]  + m[4]*m[2]*m[15] - m[4]*m[3]*m[14] - m[12]*m[2]*m[7]  + m[12]*m[3]*m[6];
    inv[10] =  m[0]*m[5]*m[15]  - m[0]*m[7]*m[13]  - m[4]*m[1]*m[15] + m[4]*m[3]*m[13] + m[12]*m[1]*m[7]  - m[12]*m[3]*m[5];
    inv[14] = -m[0]*m[5]*m[14]  + m[0]*m[6]*m[13]  + m[4]*m[1]*m[14] - m[4]*m[2]*m[13] - m[12]*m[1]*m[6]  + m[12]*m[2]*m[5];
    inv[3]  = -m[1]*m[6]*m[11]  + m[1]*m[7]*m[10]  + m[5]*m[2]*m[11] - m[5]*m[3]*m[10] - m[9]*m[2]*m[7]   + m[9]*m[3]*m[6];
    inv[7]  =  m[0]*m[6]*m[11]  - m[0]*m[7]*m[10]  - m[4]*m[2]*m[11] + m[4]*m[3]*m[10] + m[8]*m[2]*m[7]   - m[8]*m[3]*m[6];
    inv[11] = -m[0]*m[5]*m[11]  + m[0]*m[7]*m[9]   + m[4]*m[1]*m[11] - m[4]*m[3]*m[9]  - m[8]*m[1]*m[7]   + m[8]*m[3]*m[5];
    inv[15] =  m[0]*m[5]*m[10]  - m[0]*m[6]*m[9]   - m[4]*m[1]*m[10] + m[4]*m[2]*m[9]  + m[8]*m[1]*m[6]   - m[8]*m[2]*m[5];
    float det = m[0]*inv[0] + m[1]*inv[4] + m[2]*inv[8] + m[3]*inv[12];
    float idet = 1.0f / det;
    for (int i = 0; i < 16; i++) o[i] = inv[i] * idet;
}

__device__ void mul4(const float* A, const float* B, float* C) {
    for (int i = 0; i < 4; i++)
        for (int j = 0; j < 4; j++) {
            float s = 0.0f;
            for (int k = 0; k < 4; k++) s += A[4*i+k] * B[4*k+j];
            C[4*i+j] = s;
        }
}

__global__ __launch_bounds__(128) void render_k(
    const float* __restrict__ pixels,
    const float* __restrict__ Cm, const float* __restrict__ Wm, const float* __restrict__ Sm,
    const float* __restrict__ W1, const float* __restrict__ b1,
    const float* __restrict__ W2, const float* __restrict__ b2,
    const float* __restrict__ Wc1, const float* __restrict__ bc1,
    const float* __restrict__ Wc2, const float* __restrict__ bc2,
    float* __restrict__ out, int N)
{
    const int tid  = threadIdx.x;
    const int lane = tid & 63;
    const int wid  = tid >> 6;
    const int r0   = blockIdx.x * RPB;

    __shared__ float4 sG[H_];          // {W1x, W1y, W1z, b1} (phase 1, p-form)
    __shared__ float  sW2r[H_];        // raw W2 (phase 1)
    __shared__ float  sOa[RPB][H_];    // a_j * log2e, per ray
    __shared__ float2 sOc[H_];         // {c_j*log2e, w2_j*ln2}
    __shared__ float2 sCl[RPB][H_];    // {a'_j, c'_j} color, per ray
    __shared__ float4 sCw[H_];         // {wc2_0, wc2_1, wc2_2, 0}
    __shared__ float  sval[RPB][RS];   // LOGITS (acc + b2)
    __shared__ float4 sPix[RPB][FULL_];// {r,g,b,alpha}
    __shared__ float  sgeo[RPB][8];    // cam.xyz, ray.xyz, dfar, mint
    __shared__ float  sdep[RPB][2];    // dnp, dfp
    __shared__ int    sobj[RPB];

    // ---- load weights (tid = hidden unit) ----
    const float w1x = W1[tid], w1y = W1[H_ + tid], w1z = W1[2*H_ + tid];
    const float b1j = b1[tid], w2j = W2[tid];
    const float wc10 = Wc1[tid],       wc11 = Wc1[H_ + tid],  wc12 = Wc1[2*H_ + tid];
    const float wc13 = Wc1[3*H_ + tid], wc14 = Wc1[4*H_ + tid], wc15 = Wc1[5*H_ + tid];
    const float bc1j = bc1[tid];
    sG[tid]   = make_float4(w1x, w1y, w1z, b1j);
    sW2r[tid] = w2j;
    sCw[tid]  = make_float4(Wc2[tid*3 + 0], Wc2[tid*3 + 1], Wc2[tid*3 + 2], 0.0f);
    const float b2v  = b2[0];
    const float bc20 = bc2[0], bc21 = bc2[1], bc22 = bc2[2];

    // ---- geometry: lanes 0..1, one ray each ----
    if (tid < RPB) {
        const int r = r0 + tid;
        float cam[3] = {0,0,0}, ray[3] = {0,0,0};
        float dfar = 0.0f; int mint = 0;
        if (r < N) {
            float iC[16], iW[16], iS[16], T[16], M[16];
            inv4(Cm, iC); inv4(Wm, iW); inv4(Sm, iS);
            mul4(iW, iC, T); mul4(iS, T, M);
            float px_ = pixels[2*r], py_ = pixels[2*r + 1];
            float dir[3];
            for (int i = 0; i < 3; i++) {
                cam[i] = M[4*i + 3];
                float pw = M[4*i + 0]*px_ + M[4*i + 1]*py_ + M[4*i + 2] + M[4*i + 3];
                dir[i] = pw - cam[i];
            }
            float nrm = sqrtf(dir[0]*dir[0] + dir[1]*dir[1] + dir[2]*dir[2]);
            ray[0] = dir[0]/nrm; ray[1] = dir[1]/nrm; ray[2] = dir[2]/nrm;
            float rcd = ray[0]*cam[0] + ray[1]*cam[1] + ray[2]*cam[2];
            float cc  = cam[0]*cam[0] + cam[1]*cam[1] + cam[2]*cam[2];
            float under = rcd*rcd - (cc - 1.0f);
            mint = under > 0.0f;
            float s = sqrtf(mint ? under : 1.0f);
            dfar = mint ? fmaxf(s - rcd, 0.0f) : 0.0f;
        }
        sgeo[tid][0]=cam[0]; sgeo[tid][1]=cam[1]; sgeo[tid][2]=cam[2];
        sgeo[tid][3]=ray[0]; sgeo[tid][4]=ray[1]; sgeo[tid][5]=ray[2];
        sgeo[tid][6]=dfar;   sgeo[tid][7]=(float)mint;
    }
    __syncthreads();   // sync A: sgeo (and sG etc.) visible

    const float cx  = sgeo[0][0], cy  = sgeo[0][1], cz  = sgeo[0][2];
    const float r0x = sgeo[0][3], r0y = sgeo[0][4], r0z = sgeo[0][5];
    const float r1x = sgeo[1][3], r1y = sgeo[1][4], r1z = sgeo[1][5];
    const float df0 = sgeo[0][6], df1 = sgeo[1][6];

    // ---- reparam precompute (continuous paths): thread = hidden unit j ----
    {
        float aO0 = w1x*r0x + w1y*r0y + w1z*r0z;
        float aO1 = w1x*r1x + w1y*r1y + w1z*r1z;
        float cO  = w1x*cx + w1y*cy + w1z*cz + b1j;
        sOa[0][tid] = aO0 * L2E;
        sOa[1][tid] = aO1 * L2E;
        sOc[tid] = make_float2(cO * L2E, w2j * LN2);
        float base = wc10*cx + wc11*cy + wc12*cz + bc1j;
        sCl[0][tid] = make_float2(wc10*r0x + wc11*r0y + wc12*r0z,
                                  base - (wc13*r0x + wc14*r0y + wc15*r0z));
        sCl[1][tid] = make_float2(wc10*r1x + wc11*r1y + wc12*r1z,
                                  base - (wc13*r1x + wc14*r1y + wc15*r1z));
    }

    // ---- phase 1: ray-march occupancy (EXACT R3 arithmetic, store logits) ----
    {
        const float t = (float)tid * (1.0f / (RS - 1));
        float px[RPB], py[RPB], pz[RPB], acc[RPB];
        {
            float d0 = df0 * t;
            px[0] = cx + r0x*d0; py[0] = cy + r0y*d0; pz[0] = cz + r0z*d0;
            float d1 = df1 * t;
            px[1] = cx + r1x*d1; py[1] = cy + r1y*d1; pz[1] = cz + r1z*d1;
            acc[0] = 0.0f; acc[1] = 0.0f;
        }
#pragma unroll 4
        for (int j = 0; j < H_; j++) {
            float4 gw = sG[j];
            float  w2 = sW2r[j];
#pragma unroll
            for (int g = 0; g < RPB; g++) {
                float z = fmaf(px[g], gw.x, fmaf(py[g], gw.y, fmaf(pz[g], gw.z, gw.w)));
                acc[g] = fmaf(softplus_fast(z), w2, acc[g]);
            }
        }
#pragma unroll
        for (int g = 0; g < RPB; g++)
            sval[g][tid] = acc[g] + b2v;     // logit; sign(val) == sign(logit)
    }
    __syncthreads();   // sync B: sval + reparam arrays visible

    // ---- phase 2 + secant: wave g handles ray g ----
    {
        const int g = wid;
        const int l = lane;
        // two steps per lane: i0=2l, i1=2l+1; vals via sigmoid (exact R3 values)
        float v0 = sigmoid_fast(sval[g][2*l])     - 0.5f;
        float v1 = sigmoid_fast(sval[g][2*l + 1]) - 0.5f;
        int   inx = min(2*l + 2, RS - 1);
        float vn = sigmoid_fast(sval[g][inx])     - 0.5f;
        float c0, c1;
        {
            float pr = v0 * v1;
            float sg = (pr > 0.0f) ? 1.0f : ((pr < 0.0f) ? -1.0f : 0.0f);
            c0 = sg * (float)(RS - 2*l);
            if (2*l + 1 < RS - 1) {
                float pr1 = v1 * vn;
                float sg1 = (pr1 > 0.0f) ? 1.0f : ((pr1 < 0.0f) ? -1.0f : 0.0f);
                c1 = sg1 * (float)(RS - (2*l + 1));
            } else {
                c1 = 1.0f;     // i = RS-1 sentinel cost
            }
        }
        float cmin = c0; int ind = 2*l;
        if (c1 < cmin) { cmin = c1; ind = 2*l + 1; }
#pragma unroll
        for (int off = 32; off; off >>= 1) {
            float c2 = __shfl_xor(cmin, off, 64);
            int   i2 = __shfl_xor(ind,  off, 64);
            if (c2 < cmin || (c2 == cmin && i2 < ind)) { cmin = c2; ind = i2; }
        }
        const float dfar = sgeo[g][6];
        const int mask_0_free = (sigmoid_fast(sval[g][0]) - 0.5f) < 0.0f;
        const int mask_sc = cmin < 0.0f;
        const float f_low = sigmoid_fast(sval[g][ind]) - 0.5f;
        const int ind_hi = min(ind + 1, RS - 1);
        const float f_high = sigmoid_fast(sval[g][ind_hi]) - 0.5f;
        const float d_low  = dfar * ((float)ind    * (1.0f / (RS - 1)));
        const float d_high = dfar * ((float)ind_hi * (1.0f / (RS - 1)));
        const int msk = mask_sc && (f_low < 0.0f) && (sgeo[g][7] != 0.0f) && mask_0_free;

        float d_p = secant_step(f_low, f_high, d_low, d_high);
        if (msk) {   // uniform within wave
            // hoisted per-lane weights: hidden units l and l+64 (reparam, log2-domain)
            const float a0s = sOa[g][l], a1s = sOa[g][l + 64];
            const float2 oc0 = sOc[l],   oc1 = sOc[l + 64];
            float d_l = d_low, f_l = f_low, d_h = d_high, f_h = f_high;
            for (int it = 0; it < NSEC; it++) {
                float u0 = fmaf(a0s, d_p, oc0.x);
                float u1 = fmaf(a1s, d_p, oc1.x);
                float part = sp2(u0)*oc0.y + sp2(u1)*oc1.y;
#pragma unroll
                for (int off = 32; off; off >>= 1) part += __shfl_xor(part, off, 64);
                float fm = sigmoid_fast(part + b2v) - 0.5f;
                bool low = fm < 0.0f;
                d_l = low ? d_p : d_l;  f_l = low ? fm : f_l;
                d_h = low ? d_h : d_p;  f_h = low ? f_h : fm;
                d_p = secant_step(f_l, f_h, d_l, d_h);
            }
        }
        if (l == 0) {
            float d_i;
            if (!mask_0_free)      d_i = 0.0f;
            else if (msk)          d_i = d_p;
            else                   d_i = INFINITY;
            int mask_zero = (d_i == 0.0f);
            int mask_pred = isfinite(d_i);
            float dists = mask_pred ? d_i : 1.0f;
            if (mask_zero) dists = 0.0f;
            sobj[g]    = mask_pred && !mask_zero;
            sdep[g][0] = fmaxf(dists - DELTA_, 0.0f);   // dnp
            sdep[g][1] = fminf(dists + DELTA_, dfar);   // dfp
        }
    }
    __syncthreads();   // sync C

    // ---- phase 3: shading via reparam; pass0: all 128 thr, pass1: tid<64 ----
#pragma unroll
    for (int pass = 0; pass < 2; pass++) {
        int idx = tid + 128*pass;
        bool active = (pass == 0) || (tid < 64);
        if (!active) break;      // wave-uniform for wave1 (tid>=64 -> only pass 0)
        int g = idx >= FULL_;    // pass0: tid<96 -> ray0; pass1: all ray1
        int s = idx - FULL_*g;
        float d;
        if (sobj[g]) {
            float dnp = sdep[g][0], dfp = sdep[g][1];
            if (s < SOUT_) {
                d = dnp * ((float)s * (1.0f / (SOUT_ - 1)));
            } else {
                float u = (float)(s - SOUT_) * (1.0f / (SIN_ - 1));
                d = dnp * (1.0f - u) + dfp * u;
            }
        } else {
            d = sgeo[g][6] * ((float)s * (1.0f / (FULL_ - 1)));
        }
        const float*  pOa = &sOa[g][0];
        const float2* pCl = &sCl[g][0];
        float SO = 0.0f, A0 = 0.0f, A1 = 0.0f, A2 = 0.0f;
#pragma unroll 4
        for (int j = 0; j < H_; j++) {
            float  a  = pOa[j];
            float2 oc = sOc[j];
            float2 cl = pCl[j];
            float4 cw = sCw[j];
            float u = fmaf(a, d, oc.x);
            SO = fmaf(sp2(u), oc.y, SO);
            float f = fmaxf(fmaf(cl.x, d, cl.y), 0.0f);
            A0 = fmaf(f, cw.x, A0);
            A1 = fmaf(f, cw.y, A1);
            A2 = fmaf(f, cw.z, A2);
        }
        float alpha = sigmoid_fast(SO + b2v);
        sPix[g][s] = make_float4(sigmoid_fast(A0 + bc20),
                                 sigmoid_fast(A1 + bc21),
                                 sigmoid_fast(A2 + bc22),
                                 alpha);
    }
    __syncthreads();   // sync D

    // ---- alpha compositing: lanes 0..1, one ray each, 96 serial steps ----
    if (tid < RPB && r0 + tid < N) {
        float T = 1.0f, o0 = 0.0f, o1 = 0.0f, o2 = 0.0f;
        for (int k = 0; k < FULL_; k++) {
            float4 P = sPix[tid][k];
            float w = P.w * T;
            o0 = fmaf(w, P.x, o0);
            o1 = fmaf(w, P.y, o1);
            o2 = fmaf(w, P.z, o2);
            T *= (1.0f - P.w + EPSA);
        }
        const int r = r0 + tid;
        out[3*r + 0] = o0;
        out[3*r + 1] = o1;
        out[3*r + 2] = o2;
    }
}

} // namespace

extern "C" void kernel_launch(void* const* d_in, const int* in_sizes, int n_in,
                              void* d_out, int out_size, void* d_ws, size_t ws_size,
                              hipStream_t stream) {
    const float* pixels = (const float*)d_in[0];
    const float* Cm  = (const float*)d_in[1];
    const float* Wm  = (const float*)d_in[2];
    const float* Sm  = (const float*)d_in[3];
    const float* W1  = (const float*)d_in[4];
    const float* b1  = (const float*)d_in[5];
    const float* W2  = (const float*)d_in[6];
    const float* b2  = (const float*)d_in[7];
    const float* Wc1 = (const float*)d_in[8];
    const float* bc1 = (const float*)d_in[9];
    const float* Wc2 = (const float*)d_in[10];
    const float* bc2 = (const float*)d_in[11];
    float* out = (float*)d_out;

    const int N = in_sizes[0] / 2;   // pixels is (B=1, N, 2)
    const int blocks = (N + RPB - 1) / RPB;
    hipLaunchKernelGGL(render_k, dim3(blocks), dim3(128), 0, stream,
                       pixels, Cm, Wm, Sm, W1, b1, W2, b2, Wc1, bc1, Wc2, bc2, out, N);
}

// Round 5
// 118.804 us; speedup vs baseline: 4.8531x; 1.2886x over previous
//
#include <hip/hip_runtime.h>
#include <math.h>

// Renderer: occupancy-field ray marching + secant + shading.
// R5: one 64-thread wave per ray (4096 blocks), wave-synchronous.
//     Linear reparam z_j(d)=a_j*d+c_j in log2 domain for ALL MLP evals
//     (phase1 inner: 1 LDS b128 broadcast + ~6 VALU per hidden unit).
//     Phase3: pass0 = 64 samples full-wave; pass1 = 32 samples with H split
//     across wave halves + shfl_xor(32) combine. Compositing = in-register
//     wave scan (no LDS pixel buffer, no serial 96-step loop).

namespace {

constexpr int H_    = 128;
constexpr int RS    = 128;   // RAY_STEPS
constexpr int NSEC  = 8;
constexpr int SOUT_ = 32;    // STEPS_OUT
constexpr int SIN_  = 64;    // STEPS_IN
constexpr int FULL_ = 96;
constexpr float EPSA   = 1e-6f;
constexpr float DELTA_ = 0.44626032029685964f; // max(2*exp(-1.5), 0.1)
constexpr float L2E    = 1.4426950408889634f;  // log2(e)
constexpr float LN2    = 0.6931471805599453f;

// log2-domain softplus: u = z*log2e; sp2(u) = log2(1+2^u); softplus(z) = sp2(u)*ln2
__device__ __forceinline__ float sp2(float u) {
    float e = __builtin_amdgcn_exp2f(-fabsf(u));
    return fmaxf(u, 0.0f) + __builtin_amdgcn_logf(1.0f + e);
}
__device__ __forceinline__ float sigmoid_fast(float x) {
    return __builtin_amdgcn_rcpf(1.0f + __expf(-x));
}
__device__ __forceinline__ float sgnf(float p) {
    return (p > 0.0f) ? 1.0f : ((p < 0.0f) ? -1.0f : 0.0f);
}
__device__ __forceinline__ float secant_step(float f_l, float f_h, float d_l, float d_h) {
    float den = f_h - f_l;
    if (fabsf(den) > 1e-12f) return -f_l * (d_h - d_l) / den + d_l;
    return 0.5f * (d_l + d_h);
}

__device__ void inv4(const float* m, float* o) {
    float inv[16];
    inv[0]  =  m[5]*m[10]*m[15] - m[5]*m[11]*m[14] - m[9]*m[6]*m[15] + m[9]*m[7]*m[14] + m[13]*m[6]*m[11] - m[13]*m[7]*m[10];
    inv[4]  = -m[4]*m[10]*m[15] + m[4]*m[11]*m[14] + m[8]*m[6]*m[15] - m[8]*m[7]*m[14] - m[12]*m[6]*m[11] + m[12]*m[7]*m[10];
    inv[8]  =  m[4]*m[9]*m[15]  - m[4]*m[11]*m[13] - m[8]*m[5]*m[15] + m[8]*m[7]*m[13] + m[12]*m[5]*m[11] - m[12]*m[7]*m[9];
    inv[12] = -m[4]*m[9]*m[14]  + m[4]*m[10]*m[13] + m[8]*m[5]*m[14] - m[8]*m[6]*m[13] - m[12]*m[5]*m[10] + m[12]*m[6]*m[9];
    inv[1]  = -m[1]*m[10]*m[15] + m[1]*m[11]*m[14] + m[9]*m[2]*m[15] - m[9]*m[3]*m[14] - m[13]*m[2]*m[11] + m[13]*m[3]*m[10];
    inv[5]  =  m[0]*m[10]*m[15] - m[0]*m[11]*m[14] - m[8]*m[2]*m[15] + m[8]*m[3]*m[14] + m[12]*m[2]*m[11] - m[12]*m[3]*m[10];
    inv[9]  = -m[0]*m[9]*m[15]  + m[0]*m[11]*m[13] + m[8]*m[1]*m[15] - m[8]*m[3]*m[13] - m[12]*m[1]*m[11] + m[12]*m[3]*m[9];
    inv[13] =  m[0]*m[9]*m[14]  - m[0]*m[10]*m[13] - m[8]*m[1]*m[14] + m[8]*m[2]*m[13] + m[12]*m[1]*m[10] - m[12]*m[2]*m[9];
    inv[2]  =  m[1]*m[6]*m[15]  - m[1]*m[7]*m[14]  - m[5]*m[2]*m[15] + m[5]*m[3]*m[14] + m[13]*m[2]*m[7]  - m[13]*m[3]*m[6];
    inv[6]  = -m[0]*m[6]*m[15]  + m[0]*m[7]*m[14]  + m[4]*m[2]*m[15] - m[4]*m[3]*m[14] - m[12]*m[2]*m[7]  + m[12]*m[3]*m[6];
    inv[10] =  m[0]*m[5]*m[15]  - m[0]*m[7]*m[13]  - m[4]*m[1]*m[15] + m[4]*m[3]*m[13] + m[12]*m[1]*m[7]  - m[12]*m[3]*m[5];
    inv[14] = -m[0]*m[5]*m[14]  + m[0]*m[6]*m[13]  + m[4]*m[1]*m[14] - m[4]*m[2]*m[13] - m[12]*m[1]*m[6]  + m[12]*m[2]*m[5];
    inv[3]  = -m[1]*m[6]*m[11]  + m[1]*m[7]*m[10]  + m[5]*m[2]*m[11] - m[5]*m[3]*m[10] - m[9]*m[2]*m[7]   + m[9]*m[3]*m[6];
    inv[7]  =  m[0]*m[6]*m[11]  - m[0]*m[7]*m[10]  - m[4]*m[2]*m[11] + m[4]*m[3]*m[10] + m[8]*m[2]*m[7]   - m[8]*m[3]*m[6];
    inv[11] = -m[0]*m[5]*m[11]  + m[0]*m[7]*m[9]   + m[4]*m[1]*m[11] - m[4]*m[3]*m[9]  - m[8]*m[1]*m[7]   + m[8]*m[3]*m[5];
    inv[15] =  m[0]*m[5]*m[10]  - m[0]*m[6]*m[9]   - m[4]*m[1]*m[10] + m[4]*m[2]*m[9]  + m[8]*m[1]*m[6]   - m[8]*m[2]*m[5];
    float det = m[0]*inv[0] + m[1]*inv[4] + m[2]*inv[8] + m[3]*inv[12];
    float idet = 1.0f / det;
    for (int i = 0; i < 16; i++) o[i] = inv[i] * idet;
}

__device__ void mul4(const float* A, const float* B, float* C) {
    for (int i = 0; i < 4; i++)
        for (int j = 0; j < 4; j++) {
            float s = 0.0f;
            for (int k = 0; k < 4; k++) s += A[4*i+k] * B[4*k+j];
            C[4*i+j] = s;
        }
}

__global__ __launch_bounds__(64) void render_k(
    const float* __restrict__ pixels,
    const float* __restrict__ Cm, const float* __restrict__ Wm, const float* __restrict__ Sm,
    const float* __restrict__ W1, const float* __restrict__ b1,
    const float* __restrict__ W2, const float* __restrict__ b2,
    const float* __restrict__ Wc1, const float* __restrict__ bc1,
    const float* __restrict__ Wc2, const float* __restrict__ bc2,
    float* __restrict__ out, int N)
{
    const int tid = threadIdx.x;      // 0..63, one wave
    const int r   = blockIdx.x;       // one ray per block

    __shared__ float4 sPA[H_];        // {a2, c2, w2*ln2, aC}
    __shared__ float4 sPB[H_];        // {cC, wc2_0, wc2_1, wc2_2}
    __shared__ float  sval[RS];       // phase-1 logits

    // ---- geometry (uniform on all lanes; same arithmetic as R4) ----
    float cx, cy, cz, rx, ry, rz, dfar;
    int mint;
    {
        float iC[16], iW[16], iS[16], T4[16], M[16];
        inv4(Cm, iC); inv4(Wm, iW); inv4(Sm, iS);
        mul4(iW, iC, T4); mul4(iS, T4, M);
        const float px_ = pixels[2*r], py_ = pixels[2*r + 1];
        float cam[3], dir[3];
        for (int i = 0; i < 3; i++) {
            cam[i] = M[4*i + 3];
            float pw = M[4*i + 0]*px_ + M[4*i + 1]*py_ + M[4*i + 2] + M[4*i + 3];
            dir[i] = pw - cam[i];
        }
        float nrm = sqrtf(dir[0]*dir[0] + dir[1]*dir[1] + dir[2]*dir[2]);
        rx = dir[0]/nrm; ry = dir[1]/nrm; rz = dir[2]/nrm;
        cx = cam[0]; cy = cam[1]; cz = cam[2];
        float rcd = rx*cx + ry*cy + rz*cz;
        float cc  = cx*cx + cy*cy + cz*cz;
        float under = rcd*rcd - (cc - 1.0f);      // RADIUS = 1
        mint = under > 0.0f;
        float s = sqrtf(mint ? under : 1.0f);
        dfar = mint ? fmaxf(s - rcd, 0.0f) : 0.0f;
    }

    // ---- staging + reparam: lane stages hidden units tid and tid+64 ----
    float a2k[2], c2k[2], w2k[2];     // kept in regs for the secant loop
#pragma unroll
    for (int k = 0; k < 2; k++) {
        const int u = tid + 64*k;
        float w1x = W1[u], w1y = W1[H_ + u], w1z = W1[2*H_ + u];
        float b1j = b1[u], w2j = W2[u];
        float aO = (w1x*rx + w1y*ry + w1z*rz) * L2E;
        float cO = (w1x*cx + w1y*cy + w1z*cz + b1j) * L2E;
        float wl = w2j * LN2;
        a2k[k] = aO; c2k[k] = cO; w2k[k] = wl;
        float q0 = Wc1[u],        q1 = Wc1[H_ + u],  q2 = Wc1[2*H_ + u];
        float q3 = Wc1[3*H_ + u], q4 = Wc1[4*H_ + u], q5 = Wc1[5*H_ + u];
        float aC = q0*rx + q1*ry + q2*rz;
        float cC = q0*cx + q1*cy + q2*cz + bc1[u] - (q3*rx + q4*ry + q5*rz);
        sPA[u] = make_float4(aO, cO, wl, aC);
        sPB[u] = make_float4(cC, Wc2[3*u + 0], Wc2[3*u + 1], Wc2[3*u + 2]);
    }
    const float b2v  = b2[0];
    const float bc20 = bc2[0], bc21 = bc2[1], bc22 = bc2[2];
    __syncthreads();   // single wave: near-free

    // ---- phase 1: steps tid and tid+64 ----
    const float inv127 = 1.0f / (RS - 1);
    float l_a, l_b;
    {
        float d_a = dfar * ((float)tid * inv127);
        float d_b = dfar * ((float)(tid + 64) * inv127);
        float acc_a = 0.0f, acc_b = 0.0f;
#pragma unroll 8
        for (int j = 0; j < H_; j++) {
            float4 q = sPA[j];
            float ua = fmaf(q.x, d_a, q.y);
            float ub = fmaf(q.x, d_b, q.y);
            acc_a = fmaf(sp2(ua), q.z, acc_a);
            acc_b = fmaf(sp2(ub), q.z, acc_b);
        }
        l_a = acc_a + b2v;
        l_b = acc_b + b2v;
        sval[tid] = l_a; sval[tid + 64] = l_b;
    }
    __syncthreads();

    // ---- phase 2: crossing detection (val semantics == R3/R4: sigmoid-0.5) ----
    float dnp, dfp;
    int obj;
    {
        float va = sigmoid_fast(l_a) - 0.5f;
        float vb = sigmoid_fast(l_b) - 0.5f;
        float van = __shfl_down(va, 1, 64);
        float vb0 = __shfl(vb, 0, 64);
        if (tid == 63) van = vb0;               // step 64 follows step 63
        float vbn = __shfl_down(vb, 1, 64);
        float ca = sgnf(va * van) * (float)(RS - tid);
        float cb = (tid < 63) ? sgnf(vb * vbn) * (float)(64 - tid) : 1.0f;
        float cmin = ca; int ind = tid;
        if (cb < cmin) { cmin = cb; ind = tid + 64; }
#pragma unroll
        for (int off = 32; off; off >>= 1) {
            float c2 = __shfl_xor(cmin, off, 64);
            int   i2 = __shfl_xor(ind,  off, 64);
            if (c2 < cmin || (c2 == cmin && i2 < ind)) { cmin = c2; ind = i2; }
        }
        const int mask_0_free = (__shfl(va, 0, 64) < 0.0f);
        const int mask_sc = cmin < 0.0f;
        const int ind_hi = min(ind + 1, RS - 1);
        const float f_low  = sigmoid_fast(sval[ind])    - 0.5f;
        const float f_high = sigmoid_fast(sval[ind_hi]) - 0.5f;
        const float d_low  = dfar * ((float)ind    * inv127);
        const float d_high = dfar * ((float)ind_hi * inv127);
        const int msk = mask_sc && (f_low < 0.0f) && mint && mask_0_free;

        float d_p = secant_step(f_low, f_high, d_low, d_high);
        if (msk) {   // wave-uniform
            float d_l = d_low, f_l = f_low, d_h = d_high, f_h = f_high;
            for (int it = 0; it < NSEC; it++) {
                float u0 = fmaf(a2k[0], d_p, c2k[0]);
                float u1 = fmaf(a2k[1], d_p, c2k[1]);
                float part = sp2(u0)*w2k[0] + sp2(u1)*w2k[1];
#pragma unroll
                for (int off = 32; off; off >>= 1) part += __shfl_xor(part, off, 64);
                float fm = sigmoid_fast(part + b2v) - 0.5f;
                bool low = fm < 0.0f;
                d_l = low ? d_p : d_l;  f_l = low ? fm : f_l;
                d_h = low ? d_h : d_p;  f_h = low ? f_h : fm;
                d_p = secant_step(f_l, f_h, d_l, d_h);
            }
        }
        // depth interval selection (uniform)
        float d_i;
        if (!mask_0_free)      d_i = 0.0f;
        else if (msk)          d_i = d_p;
        else                   d_i = INFINITY;
        int mask_zero = (d_i == 0.0f);
        int mask_pred = isfinite(d_i);
        float dists = mask_pred ? d_i : 1.0f;
        if (mask_zero) dists = 0.0f;
        obj = mask_pred && !mask_zero;
        dnp = fmaxf(dists - DELTA_, 0.0f);
        dfp = fminf(dists + DELTA_, dfar);
    }

    // ---- sample depth helper (inline twice) ----
    auto sample_d = [&](int s) -> float {
        if (obj) {
            if (s < SOUT_) return dnp * ((float)s * (1.0f / (SOUT_ - 1)));
            float u = (float)(s - SOUT_) * (1.0f / (SIN_ - 1));
            return dnp * (1.0f - u) + dfp * u;
        }
        return dfar * ((float)s * (1.0f / (FULL_ - 1)));
    };

    // ---- phase 3, pass 0: samples 0..63, full j loop ----
    float alpha0, r0c, g0c, b0c;
    {
        const float d = sample_d(tid);
        float SO = 0.0f, A0 = 0.0f, A1 = 0.0f, A2 = 0.0f;
#pragma unroll 4
        for (int j = 0; j < H_; j++) {
            float4 qa = sPA[j];
            float4 qb = sPB[j];
            float u = fmaf(qa.x, d, qa.y);
            SO = fmaf(sp2(u), qa.z, SO);
            float f = fmaxf(fmaf(qa.w, d, qb.x), 0.0f);
            A0 = fmaf(f, qb.y, A0);
            A1 = fmaf(f, qb.z, A1);
            A2 = fmaf(f, qb.w, A2);
        }
        alpha0 = sigmoid_fast(SO + b2v);
        r0c = sigmoid_fast(A0 + bc20);
        g0c = sigmoid_fast(A1 + bc21);
        b0c = sigmoid_fast(A2 + bc22);
    }

    // ---- phase 3, pass 1: samples 64..95; H split across wave halves ----
    float alpha1, r1c, g1c, b1c;
    {
        const int s1 = 64 + (tid & 31);
        const int jb = (tid >> 5) * 64;      // lanes 0-31: j 0..63; 32-63: j 64..127
        const float d = sample_d(s1);
        float SO = 0.0f, A0 = 0.0f, A1 = 0.0f, A2 = 0.0f;
#pragma unroll 4
        for (int j2 = 0; j2 < 64; j2++) {
            int j = jb + j2;
            float4 qa = sPA[j];
            float4 qb = sPB[j];
            float u = fmaf(qa.x, d, qa.y);
            SO = fmaf(sp2(u), qa.z, SO);
            float f = fmaxf(fmaf(qa.w, d, qb.x), 0.0f);
            A0 = fmaf(f, qb.y, A0);
            A1 = fmaf(f, qb.z, A1);
            A2 = fmaf(f, qb.w, A2);
        }
        SO += __shfl_xor(SO, 32, 64);
        A0 += __shfl_xor(A0, 32, 64);
        A1 += __shfl_xor(A1, 32, 64);
        A2 += __shfl_xor(A2, 32, 64);
        alpha1 = sigmoid_fast(SO + b2v);
        r1c = sigmoid_fast(A0 + bc20);
        g1c = sigmoid_fast(A1 + bc21);
        b1c = sigmoid_fast(A2 + bc22);
    }

    // ---- compositing: in-register wave scan over 96 ordered samples ----
    {
        // segment A: sample tid on lane tid (all 64 real)
        float mA = 1.0f - alpha0 + EPSA;
        float p = mA;
#pragma unroll
        for (int off = 1; off < 64; off <<= 1) {
            float v = __shfl_up(p, off, 64);
            if (tid >= off) p *= v;
        }
        float TexA = __shfl_up(p, 1, 64);
        if (tid == 0) TexA = 1.0f;
        float TA = __shfl(p, 63, 64);          // total product of segment A
        float wA = alpha0 * TexA;

        // segment B: sample 64+tid on lane tid (lanes 0..31 real, rest identity)
        float mB = (tid < 32) ? (1.0f - alpha1 + EPSA) : 1.0f;
        float pb = mB;
#pragma unroll
        for (int off = 1; off < 32; off <<= 1) {
            float v = __shfl_up(pb, off, 64);
            if (tid >= off) pb *= v;
        }
        float TexB = __shfl_up(pb, 1, 64);
        if (tid == 0) TexB = 1.0f;
        float wB = (tid < 32) ? alpha1 * TexB * TA : 0.0f;

        float s0 = wA*r0c + wB*r1c;
        float s1 = wA*g0c + wB*g1c;
        float s2 = wA*b0c + wB*b1c;
#pragma unroll
        for (int off = 32; off; off >>= 1) {
            s0 += __shfl_xor(s0, off, 64);
            s1 += __shfl_xor(s1, off, 64);
            s2 += __shfl_xor(s2, off, 64);
        }
        if (tid == 0) {
            out[3*r + 0] = s0;
            out[3*r + 1] = s1;
            out[3*r + 2] = s2;
        }
    }
}

} // namespace

extern "C" void kernel_launch(void* const* d_in, const int* in_sizes, int n_in,
                              void* d_out, int out_size, void* d_ws, size_t ws_size,
                              hipStream_t stream) {
    const float* pixels = (const float*)d_in[0];
    const float* Cm  = (const float*)d_in[1];
    const float* Wm  = (const float*)d_in[2];
    const float* Sm  = (const float*)d_in[3];
    const float* W1  = (const float*)d_in[4];
    const float* b1  = (const float*)d_in[5];
    const float* W2  = (const float*)d_in[6];
    const float* b2  = (const float*)d_in[7];
    const float* Wc1 = (const float*)d_in[8];
    const float* bc1 = (const float*)d_in[9];
    const float* Wc2 = (const float*)d_in[10];
    const float* bc2 = (const float*)d_in[11];
    float* out = (float*)d_out;

    const int N = in_sizes[0] / 2;   // pixels is (B=1, N, 2)
    hipLaunchKernelGGL(render_k, dim3(N), dim3(64), 0, stream,
                       pixels, Cm, Wm, Sm, W1, b1, W2, b2, Wc1, bc1, Wc2, bc2, out, N);
}

// Round 6
// 113.920 us; speedup vs baseline: 5.0611x; 1.0429x over previous
//
#include <hip/hip_runtime.h>
#include <math.h>

// Renderer: occupancy-field ray marching + secant + shading.
// R6: one 64-thread wave per ray. Packed-f32 (v_pk_fma_f32) math: phase1 pairs
//     the two ray-steps per lane, phase3 pairs hidden units (pair-major LDS).
//     Softplus = exp2 + deg-6 poly log2(1+e) (one transcendental per element).
//     Geometry: single inv4 spread over lanes 0..2 + lane-parallel mat-muls.
//     dfar==0 fast path: single MLP eval + shared compositing.

namespace {

constexpr int H_    = 128;
constexpr int RS    = 128;   // RAY_STEPS
constexpr int NSEC  = 8;
constexpr int SOUT_ = 32;    // STEPS_OUT
constexpr int SIN_  = 64;    // STEPS_IN
constexpr int FULL_ = 96;
constexpr float EPSA   = 1e-6f;
constexpr float DELTA_ = 0.44626032029685964f; // max(2*exp(-1.5), 0.1)
constexpr float L2E    = 1.4426950408889634f;  // log2(e)
constexpr float LN2    = 0.6931471805599453f;

typedef __attribute__((ext_vector_type(2))) float f2;

__device__ __forceinline__ f2 s2(float v) { return f2{v, v}; }

// deg-6 poly for log2(1+e), e in [0,1], via t = 2e-1 (Taylor of log2(1.5+t/2)),
// max err ~1e-4 (alternating tail). Coefficients L2E/(k*3^k).
constexpr float PC0 =  0.5849625007211562f;
constexpr float PC1 =  0.4808983469629878f;
constexpr float PC2 = -0.0801497244938313f;
constexpr float PC3 =  0.0178110498875181f;
constexpr float PC4 = -0.0044527624718795f;
constexpr float PC5 =  0.0011873633258345f;
constexpr float PC6 = -0.0003298231460651f;

// packed log2-domain softplus: sp2(u) = max(u,0) + log2(1 + 2^-|u|)
__device__ __forceinline__ f2 sp2p(f2 u) {
    f2 e;
    e.x = __builtin_amdgcn_exp2f(-fabsf(u.x));
    e.y = __builtin_amdgcn_exp2f(-fabsf(u.y));
    f2 t = e + e - 1.0f;
    f2 p = s2(PC6);
    p = __builtin_elementwise_fma(p, t, s2(PC5));
    p = __builtin_elementwise_fma(p, t, s2(PC4));
    p = __builtin_elementwise_fma(p, t, s2(PC3));
    p = __builtin_elementwise_fma(p, t, s2(PC2));
    p = __builtin_elementwise_fma(p, t, s2(PC1));
    p = __builtin_elementwise_fma(p, t, s2(PC0));
    return __builtin_elementwise_max(u, s2(0.0f)) + p;
}

__device__ __forceinline__ float sigmoid_fast(float x) {
    return __builtin_amdgcn_rcpf(1.0f + __expf(-x));
}
__device__ __forceinline__ float sgnf(float p) {
    return (p > 0.0f) ? 1.0f : ((p < 0.0f) ? -1.0f : 0.0f);
}
__device__ __forceinline__ float secant_step(float f_l, float f_h, float d_l, float d_h) {
    float den = f_h - f_l;
    if (fabsf(den) > 1e-12f) return -f_l * (d_h - d_l) / den + d_l;
    return 0.5f * (d_l + d_h);
}

__device__ void inv4(const float* m, float* o) {
    float inv[16];
    inv[0]  =  m[5]*m[10]*m[15] - m[5]*m[11]*m[14] - m[9]*m[6]*m[15] + m[9]*m[7]*m[14] + m[13]*m[6]*m[11] - m[13]*m[7]*m[10];
    inv[4]  = -m[4]*m[10]*m[15] + m[4]*m[11]*m[14] + m[8]*m[6]*m[15] - m[8]*m[7]*m[14] - m[12]*m[6]*m[11] + m[12]*m[7]*m[10];
    inv[8]  =  m[4]*m[9]*m[15]  - m[4]*m[11]*m[13] - m[8]*m[5]*m[15] + m[8]*m[7]*m[13] + m[12]*m[5]*m[11] - m[12]*m[7]*m[9];
    inv[12] = -m[4]*m[9]*m[14]  + m[4]*m[10]*m[13] + m[8]*m[5]*m[14] - m[8]*m[6]*m[13] - m[12]*m[5]*m[10] + m[12]*m[6]*m[9];
    inv[1]  = -m[1]*m[10]*m[15] + m[1]*m[11]*m[14] + m[9]*m[2]*m[15] - m[9]*m[3]*m[14] - m[13]*m[2]*m[11] + m[13]*m[3]*m[10];
    inv[5]  =  m[0]*m[10]*m[15] - m[0]*m[11]*m[14] - m[8]*m[2]*m[15] + m[8]*m[3]*m[14] + m[12]*m[2]*m[11] - m[12]*m[3]*m[10];
    inv[9]  = -m[0]*m[9]*m[15]  + m[0]*m[11]*m[13] + m[8]*m[1]*m[15] - m[8]*m[3]*m[13] - m[12]*m[1]*m[11] + m[12]*m[3]*m[9];
    inv[13] =  m[0]*m[9]*m[14]  - m[0]*m[10]*m[13] - m[8]*m[1]*m[14] + m[8]*m[2]*m[13] + m[12]*m[1]*m[10] - m[12]*m[2]*m[9];
    inv[2]  =  m[1]*m[6]*m[15]  - m[1]*m[7]*m[14]  - m[5]*m[2]*m[15] + m[5]*m[3]*m[14] + m[13]*m[2]*m[7]  - m[13]*m[3]*m[6];
    inv[6]  = -m[0]*m[6]*m[15]  + m[0]*m[7]*m[14]  + m[4]*m[2]*m[15] - m[4]*m[3]*m[14] - m[12]*m[2]*m[7]  + m[12]*m[3]*m[6];
    inv[10] =  m[0]*m[5]*m[15]  - m[0]*m[7]*m[13]  - m[4]*m[1]*m[15] + m[4]*m[3]*m[13] + m[12]*m[1]*m[7]  - m[12]*m[3]*m[5];
    inv[14] = -m[0]*m[5]*m[14]  + m[0]*m[6]*m[13]  + m[4]*m[1]*m[14] - m[4]*m[2]*m[13] - m[12]*m[1]*m[6]  + m[12]*m[2]*m[5];
    inv[3]  = -m[1]*m[6]*m[11]  + m[1]*m[7]*m[10]  + m[5]*m[2]*m[11] - m[5]*m[3]*m[10] - m[9]*m[2]*m[7]   + m[9]*m[3]*m[6];
    inv[7]  =  m[0]*m[6]*m[11]  - m[0]*m[7]*m[10]  - m[4]*m[2]*m[11] + m[4]*m[3]*m[10] + m[8]*m[2]*m[7]   - m[8]*m[3]*m[6];
    inv[11] = -m[0]*m[5]*m[11]  + m[0]*m[7]*m[9]   + m[4]*m[1]*m[11] - m[4]*m[3]*m[9]  - m[8]*m[1]*m[7]   + m[8]*m[3]*m[5];
    inv[15] =  m[0]*m[5]*m[10]  - m[0]*m[6]*m[9]   - m[4]*m[1]*m[10] + m[4]*m[2]*m[9]  + m[8]*m[1]*m[6]   - m[8]*m[2]*m[5];
    float det = m[0]*inv[0] + m[1]*inv[4] + m[2]*inv[8] + m[3]*inv[12];
    float idet = 1.0f / det;
    for (int i = 0; i < 16; i++) o[i] = inv[i] * idet;
}

__global__ __launch_bounds__(64) void render_k(
    const float* __restrict__ pixels,
    const float* __restrict__ Cm, const float* __restrict__ Wm, const float* __restrict__ Sm,
    const float* __restrict__ W1, const float* __restrict__ b1,
    const float* __restrict__ W2, const float* __restrict__ b2,
    const float* __restrict__ Wc1, const float* __restrict__ bc1,
    const float* __restrict__ Wc2, const float* __restrict__ bc2,
    float* __restrict__ out, int N)
{
    const int tid = threadIdx.x;      // 0..63, one wave
    const int r   = blockIdx.x;       // one ray per block

    // pair-major weight LDS: slot j2 holds hidden units 2*j2, 2*j2+1
    __shared__ float4 sP0[H_/2];      // {a,a', c,c'}       (occ, log2 domain)
    __shared__ float4 sP1[H_/2];      // {w,w', aC,aC'}     (w = w2*ln2)
    __shared__ float4 sP2[H_/2];      // {cC,cC', w0,w0'}
    __shared__ float4 sP3[H_/2];      // {w1,w1', w2,w2'}
    __shared__ float  sval[RS];       // phase-1 logits
    __shared__ float  sInv[3][16];    // iC, iW, iS
    __shared__ float  sT[16], sM[16];

    // ---- geometry: one inv4, matrices spread over lanes 0..2 ----
    {
        const float* mm = (tid == 0) ? Cm : ((tid == 1) ? Wm : Sm);
        float o[16];
        inv4(mm, o);                  // control-uniform; data-divergent
        if (tid < 3)
            for (int k = 0; k < 16; k++) sInv[tid][k] = o[k];
    }
    __syncthreads();
    if (tid < 16) {                   // T = iW @ iC
        int row = tid >> 2, col = tid & 3;
        float s = 0.0f;
        for (int k = 0; k < 4; k++) s += sInv[1][row*4 + k] * sInv[0][k*4 + col];
        sT[tid] = s;
    }
    __syncthreads();
    if (tid < 16) {                   // M = iS @ T
        int row = tid >> 2, col = tid & 3;
        float s = 0.0f;
        for (int k = 0; k < 4; k++) s += sInv[2][row*4 + k] * sT[k*4 + col];
        sM[tid] = s;
    }
    __syncthreads();

    float cx, cy, cz, rx, ry, rz, dfar;
    int mint;
    {
        const float px_ = pixels[2*r], py_ = pixels[2*r + 1];
        float cam[3], dir[3];
        for (int i = 0; i < 3; i++) {
            cam[i] = sM[4*i + 3];
            float pw = sM[4*i + 0]*px_ + sM[4*i + 1]*py_ + sM[4*i + 2] + sM[4*i + 3];
            dir[i] = pw - cam[i];
        }
        float nrm = sqrtf(dir[0]*dir[0] + dir[1]*dir[1] + dir[2]*dir[2]);
        rx = dir[0]/nrm; ry = dir[1]/nrm; rz = dir[2]/nrm;
        cx = cam[0]; cy = cam[1]; cz = cam[2];
        float rcd = rx*cx + ry*cy + rz*cz;
        float cc  = cx*cx + cy*cy + cz*cz;
        float under = rcd*rcd - (cc - 1.0f);      // RADIUS = 1
        mint = under > 0.0f;
        float s = sqrtf(mint ? under : 1.0f);
        dfar = mint ? fmaxf(s - rcd, 0.0f) : 0.0f;
    }

    // ---- staging + reparam: lane stages hidden units 2*tid, 2*tid+1 ----
    float a2k[2], c2k[2], w2k[2];               // occ (secant + fast path)
    float cCr[2], w0r[2], w1r[2], w2r[2];       // color (fast path)
#pragma unroll
    for (int k = 0; k < 2; k++) {
        const int u = 2*tid + k;
        float w1x = W1[u], w1y = W1[H_ + u], w1z = W1[2*H_ + u];
        float b1j = b1[u], w2j = W2[u];
        a2k[k] = (w1x*rx + w1y*ry + w1z*rz) * L2E;
        c2k[k] = (w1x*cx + w1y*cy + w1z*cz + b1j) * L2E;
        w2k[k] = w2j * LN2;
        float q0 = Wc1[u],        q1 = Wc1[H_ + u],  q2 = Wc1[2*H_ + u];
        float q3 = Wc1[3*H_ + u], q4 = Wc1[4*H_ + u], q5 = Wc1[5*H_ + u];
        float aC = q0*rx + q1*ry + q2*rz;
        cCr[k] = q0*cx + q1*cy + q2*cz + bc1[u] - (q3*rx + q4*ry + q5*rz);
        w0r[k] = Wc2[3*u + 0]; w1r[k] = Wc2[3*u + 1]; w2r[k] = Wc2[3*u + 2];
        if (k == 0) {
            sP0[tid].x = a2k[0]; sP0[tid].z = c2k[0];
            sP1[tid].x = w2k[0]; sP1[tid].z = aC;
            sP2[tid].x = cCr[0]; sP2[tid].z = w0r[0];
            sP3[tid].x = w1r[0]; sP3[tid].z = w2r[0];
        } else {
            sP0[tid].y = a2k[1]; sP0[tid].w = c2k[1];
            sP1[tid].y = w2k[1]; sP1[tid].w = aC;
            sP2[tid].y = cCr[1]; sP2[tid].w = w0r[1];
            sP3[tid].y = w1r[1]; sP3[tid].w = w2r[1];
        }
    }
    const float b2v  = b2[0];
    const float bc20 = bc2[0], bc21 = bc2[1], bc22 = bc2[2];
    __syncthreads();

    float alpha0, r0c, g0c, b0c;      // sample tid
    float alpha1, r1c, g1c, b1c;      // sample 64 + (tid&31)

    if (dfar == 0.0f) {
        // ---- fast path: all 96 samples sit at the camera point ----
        f2 sp = sp2p(f2{c2k[0], c2k[1]});
        float part = sp.x*w2k[0] + sp.y*w2k[1];
        f2 ff = __builtin_elementwise_max(f2{cCr[0], cCr[1]}, s2(0.0f));
        float A0 = ff.x*w0r[0] + ff.y*w0r[1];
        float A1 = ff.x*w1r[0] + ff.y*w1r[1];
        float A2 = ff.x*w2r[0] + ff.y*w2r[1];
#pragma unroll
        for (int off = 32; off; off >>= 1) {
            part += __shfl_xor(part, off, 64);
            A0   += __shfl_xor(A0,   off, 64);
            A1   += __shfl_xor(A1,   off, 64);
            A2   += __shfl_xor(A2,   off, 64);
        }
        alpha0 = sigmoid_fast(part + b2v);
        r0c = sigmoid_fast(A0 + bc20);
        g0c = sigmoid_fast(A1 + bc21);
        b0c = sigmoid_fast(A2 + bc22);
        alpha1 = alpha0; r1c = r0c; g1c = g0c; b1c = b0c;
    } else {
        // ---- phase 1: steps tid and tid+64, packed over the step pair ----
        const float inv127 = 1.0f / (RS - 1);
        float l_a, l_b;
        {
            f2 d2 = f2{ dfar * ((float)tid * inv127),
                        dfar * ((float)(tid + 64) * inv127) };
            f2 acc = s2(0.0f);
#pragma unroll 4
            for (int j2 = 0; j2 < H_/2; j2++) {
                float4 q0 = sP0[j2];
                float4 q1 = sP1[j2];
                f2 uA = __builtin_elementwise_fma(s2(q0.x), d2, s2(q0.z));
                f2 uB = __builtin_elementwise_fma(s2(q0.y), d2, s2(q0.w));
                acc = __builtin_elementwise_fma(sp2p(uA), s2(q1.x), acc);
                acc = __builtin_elementwise_fma(sp2p(uB), s2(q1.y), acc);
            }
            l_a = acc.x + b2v;
            l_b = acc.y + b2v;
            sval[tid] = l_a; sval[tid + 64] = l_b;
        }
        __syncthreads();

        // ---- phase 2: crossing detection + secant (val = sigmoid-0.5) ----
        float dnp, dfp;
        int obj;
        {
            float va = sigmoid_fast(l_a) - 0.5f;
            float vb = sigmoid_fast(l_b) - 0.5f;
            float van = __shfl_down(va, 1, 64);
            float vb0 = __shfl(vb, 0, 64);
            if (tid == 63) van = vb0;
            float vbn = __shfl_down(vb, 1, 64);
            float ca = sgnf(va * van) * (float)(RS - tid);
            float cb = (tid < 63) ? sgnf(vb * vbn) * (float)(64 - tid) : 1.0f;
            float cmin = ca; int ind = tid;
            if (cb < cmin) { cmin = cb; ind = tid + 64; }
#pragma unroll
            for (int off = 32; off; off >>= 1) {
                float c2 = __shfl_xor(cmin, off, 64);
                int   i2 = __shfl_xor(ind,  off, 64);
                if (c2 < cmin || (c2 == cmin && i2 < ind)) { cmin = c2; ind = i2; }
            }
            const int mask_0_free = (__shfl(va, 0, 64) < 0.0f);
            const int mask_sc = cmin < 0.0f;
            const int ind_hi = min(ind + 1, RS - 1);
            const float f_low  = sigmoid_fast(sval[ind])    - 0.5f;
            const float f_high = sigmoid_fast(sval[ind_hi]) - 0.5f;
            const float d_low  = dfar * ((float)ind    * inv127);
            const float d_high = dfar * ((float)ind_hi * inv127);
            const int msk = mask_sc && (f_low < 0.0f) && mint && mask_0_free;

            float d_p = secant_step(f_low, f_high, d_low, d_high);
            if (msk) {   // wave-uniform
                float d_l = d_low, f_l = f_low, d_h = d_high, f_h = f_high;
                for (int it = 0; it < NSEC; it++) {
                    f2 u2 = __builtin_elementwise_fma(f2{a2k[0], a2k[1]}, s2(d_p),
                                                      f2{c2k[0], c2k[1]});
                    f2 sp = sp2p(u2);
                    float part = sp.x*w2k[0] + sp.y*w2k[1];
#pragma unroll
                    for (int off = 32; off; off >>= 1) part += __shfl_xor(part, off, 64);
                    float fm = sigmoid_fast(part + b2v) - 0.5f;
                    bool low = fm < 0.0f;
                    d_l = low ? d_p : d_l;  f_l = low ? fm : f_l;
                    d_h = low ? d_h : d_p;  f_h = low ? f_h : fm;
                    d_p = secant_step(f_l, f_h, d_l, d_h);
                }
            }
            float d_i;
            if (!mask_0_free)      d_i = 0.0f;
            else if (msk)          d_i = d_p;
            else                   d_i = INFINITY;
            int mask_zero = (d_i == 0.0f);
            int mask_pred = isfinite(d_i);
            float dists = mask_pred ? d_i : 1.0f;
            if (mask_zero) dists = 0.0f;
            obj = mask_pred && !mask_zero;
            dnp = fmaxf(dists - DELTA_, 0.0f);
            dfp = fminf(dists + DELTA_, dfar);
        }

        auto sample_d = [&](int s) -> float {
            if (obj) {
                if (s < SOUT_) return dnp * ((float)s * (1.0f / (SOUT_ - 1)));
                float u = (float)(s - SOUT_) * (1.0f / (SIN_ - 1));
                return dnp * (1.0f - u) + dfp * u;
            }
            return dfar * ((float)s * (1.0f / (FULL_ - 1)));
        };

        // ---- phase 3, pass 0: samples 0..63, hidden units paired ----
        {
            const f2 dd = s2(sample_d(tid));
            f2 SO = s2(0.0f), A0 = s2(0.0f), A1 = s2(0.0f), A2 = s2(0.0f);
#pragma unroll 4
            for (int j2 = 0; j2 < H_/2; j2++) {
                float4 q0 = sP0[j2];
                float4 q1 = sP1[j2];
                float4 q2 = sP2[j2];
                float4 q3 = sP3[j2];
                f2 u = __builtin_elementwise_fma(f2{q0.x, q0.y}, dd, f2{q0.z, q0.w});
                SO = __builtin_elementwise_fma(sp2p(u), f2{q1.x, q1.y}, SO);
                f2 f = __builtin_elementwise_max(
                           __builtin_elementwise_fma(f2{q1.z, q1.w}, dd, f2{q2.x, q2.y}),
                           s2(0.0f));
                A0 = __builtin_elementwise_fma(f, f2{q2.z, q2.w}, A0);
                A1 = __builtin_elementwise_fma(f, f2{q3.x, q3.y}, A1);
                A2 = __builtin_elementwise_fma(f, f2{q3.z, q3.w}, A2);
            }
            alpha0 = sigmoid_fast(SO.x + SO.y + b2v);
            r0c = sigmoid_fast(A0.x + A0.y + bc20);
            g0c = sigmoid_fast(A1.x + A1.y + bc21);
            b0c = sigmoid_fast(A2.x + A2.y + bc22);
        }

        // ---- phase 3, pass 1: samples 64..95; pair-range split by half-wave ----
        {
            const int s1 = 64 + (tid & 31);
            const int jb = (tid >> 5) * (H_/4);   // 0 or 32 pair-slots
            const f2 dd = s2(sample_d(s1));
            f2 SO = s2(0.0f), A0 = s2(0.0f), A1 = s2(0.0f), A2 = s2(0.0f);
#pragma unroll 4
            for (int j2 = jb; j2 < jb + H_/4; j2++) {
                float4 q0 = sP0[j2];
                float4 q1 = sP1[j2];
                float4 q2 = sP2[j2];
                float4 q3 = sP3[j2];
                f2 u = __builtin_elementwise_fma(f2{q0.x, q0.y}, dd, f2{q0.z, q0.w});
                SO = __builtin_elementwise_fma(sp2p(u), f2{q1.x, q1.y}, SO);
                f2 f = __builtin_elementwise_max(
                           __builtin_elementwise_fma(f2{q1.z, q1.w}, dd, f2{q2.x, q2.y}),
                           s2(0.0f));
                A0 = __builtin_elementwise_fma(f, f2{q2.z, q2.w}, A0);
                A1 = __builtin_elementwise_fma(f, f2{q3.x, q3.y}, A1);
                A2 = __builtin_elementwise_fma(f, f2{q3.z, q3.w}, A2);
            }
            float SOs = SO.x + SO.y, A0s = A0.x + A0.y;
            float A1s = A1.x + A1.y, A2s = A2.x + A2.y;
            SOs += __shfl_xor(SOs, 32, 64);
            A0s += __shfl_xor(A0s, 32, 64);
            A1s += __shfl_xor(A1s, 32, 64);
            A2s += __shfl_xor(A2s, 32, 64);
            alpha1 = sigmoid_fast(SOs + b2v);
            r1c = sigmoid_fast(A0s + bc20);
            g1c = sigmoid_fast(A1s + bc21);
            b1c = sigmoid_fast(A2s + bc22);
        }
    }

    // ---- compositing: in-register wave scan over 96 ordered samples ----
    {
        float mA = 1.0f - alpha0 + EPSA;
        float p = mA;
#pragma unroll
        for (int off = 1; off < 64; off <<= 1) {
            float v = __shfl_up(p, off, 64);
            if (tid >= off) p *= v;
        }
        float TexA = __shfl_up(p, 1, 64);
        if (tid == 0) TexA = 1.0f;
        float TA = __shfl(p, 63, 64);
        float wA = alpha0 * TexA;

        float mB = (tid < 32) ? (1.0f - alpha1 + EPSA) : 1.0f;
        float pb = mB;
#pragma unroll
        for (int off = 1; off < 32; off <<= 1) {
            float v = __shfl_up(pb, off, 64);
            if (tid >= off) pb *= v;
        }
        float TexB = __shfl_up(pb, 1, 64);
        if (tid == 0) TexB = 1.0f;
        float wB = (tid < 32) ? alpha1 * TexB * TA : 0.0f;

        float s0 = wA*r0c + wB*r1c;
        float s1 = wA*g0c + wB*g1c;
        float s2v = wA*b0c + wB*b1c;
#pragma unroll
        for (int off = 32; off; off >>= 1) {
            s0  += __shfl_xor(s0,  off, 64);
            s1  += __shfl_xor(s1,  off, 64);
            s2v += __shfl_xor(s2v, off, 64);
        }
        if (tid == 0) {
            out[3*r + 0] = s0;
            out[3*r + 1] = s1;
            out[3*r + 2] = s2v;
        }
    }
}

} // namespace

extern "C" void kernel_launch(void* const* d_in, const int* in_sizes, int n_in,
                              void* d_out, int out_size, void* d_ws, size_t ws_size,
                              hipStream_t stream) {
    const float* pixels = (const float*)d_in[0];
    const float* Cm  = (const float*)d_in[1];
    const float* Wm  = (const float*)d_in[2];
    const float* Sm  = (const float*)d_in[3];
    const float* W1  = (const float*)d_in[4];
    const float* b1  = (const float*)d_in[5];
    const float* W2  = (const float*)d_in[6];
    const float* b2  = (const float*)d_in[7];
    const float* Wc1 = (const float*)d_in[8];
    const float* bc1 = (const float*)d_in[9];
    const float* Wc2 = (const float*)d_in[10];
    const float* bc2 = (const float*)d_in[11];
    float* out = (float*)d_out;

    const int N = in_sizes[0] / 2;   // pixels is (B=1, N, 2)
    hipLaunchKernelGGL(render_k, dim3(N), dim3(64), 0, stream,
                       pixels, Cm, Wm, Sm, W1, b1, W2, b2, Wc1, bc1, Wc2, bc2, out, N);
}